// Round 1
// baseline (1413.395 us; speedup 1.0000x reference)
//
#include <hip/hip_runtime.h>

#define HID 128
#define BN_EPS 1e-5f

// ---------------- CSR build ----------------

__global__ void k_count(const int* __restrict__ dst, int* __restrict__ cnt, int e) {
  int i = blockIdx.x * blockDim.x + threadIdx.x;
  if (i < e) atomicAdd(&cnt[dst[i]], 1);
}

// single-block hierarchical exclusive scan: cursor(deg in) -> row_ptr, cursor(excl out)
__global__ void k_scan(int* __restrict__ cursor, int* __restrict__ row_ptr, int n) {
  __shared__ int wsum[16];
  __shared__ int wincl[16];
  __shared__ int s_carry;
  int tid = threadIdx.x;
  int lane = tid & 63;
  int wid = tid >> 6;
  if (tid == 0) s_carry = 0;
  __syncthreads();
  for (int base = 0; base < n; base += 1024) {
    int i = base + tid;
    int v = (i < n) ? cursor[i] : 0;
    int x = v;
#pragma unroll
    for (int off = 1; off < 64; off <<= 1) {
      int y = __shfl_up(x, off, 64);
      if (lane >= off) x += y;
    }
    if (lane == 63) wsum[wid] = x;
    __syncthreads();
    if (wid == 0) {
      int s = (lane < 16) ? wsum[lane] : 0;
#pragma unroll
      for (int off = 1; off < 16; off <<= 1) {
        int y = __shfl_up(s, off, 64);
        if (lane >= off) s += y;
      }
      if (lane < 16) wincl[lane] = s;
    }
    __syncthreads();
    int carry = s_carry;
    int woff = (wid == 0) ? 0 : wincl[wid - 1];
    int excl = carry + woff + (x - v);
    if (i < n) { row_ptr[i] = excl; cursor[i] = excl; }
    __syncthreads();
    if (tid == 0) s_carry = carry + wincl[15];
    __syncthreads();
  }
  if (tid == 0) row_ptr[n] = s_carry;
}

__global__ void k_invdeg(const int* __restrict__ row_ptr, float* __restrict__ inv_deg, int n) {
  int i = blockIdx.x * blockDim.x + threadIdx.x;
  if (i < n) {
    int d = row_ptr[i + 1] - row_ptr[i];
    inv_deg[i] = 1.0f / (float)max(d, 1);
  }
}

__global__ void k_fill(const int* __restrict__ src, const int* __restrict__ dst,
                       int* __restrict__ cursor, int* __restrict__ col, int e) {
  int i = blockIdx.x * blockDim.x + threadIdx.x;
  if (i < e) {
    int d = dst[i];
    int pos = atomicAdd(&cursor[d], 1);
    col[pos] = src[i];
  }
}

// ---------------- SpMM: agg[i] = inv_deg[i] * sum_{j in N(i)} h[j] ----------------
// one 64-lane wave per node, 2 channels/lane (float2)

__global__ void k_spmm(const float* __restrict__ hin, const int* __restrict__ row_ptr,
                       const int* __restrict__ col, const float* __restrict__ inv_deg,
                       float* __restrict__ agg, int n) {
  int node = blockIdx.x * 4 + (threadIdx.x >> 6);
  if (node >= n) return;
  int lane = threadIdx.x & 63;
  int beg = row_ptr[node], end = row_ptr[node + 1];
  float ax = 0.f, ay = 0.f;
  const float* base = hin + (lane << 1);
  for (int e = beg; e < end; ++e) {
    int s = col[e];
    float2 v = *(const float2*)(base + ((size_t)s << 7));
    ax += v.x; ay += v.y;
  }
  float w = inv_deg[node];
  *(float2*)(agg + ((size_t)node << 7) + (lane << 1)) = make_float2(ax * w, ay * w);
}

// ---------------- dense: h_out = relu(bn(agg@Wl + h@Wr + b)) ----------------
// 64-node tile per 256-thread block; thread = (tx 0..31 -> 4 cols, ty 0..7 -> 8 rows)

__global__ __launch_bounds__(256) void k_dense(
    const float* __restrict__ hin, const float* __restrict__ agg,
    const float* __restrict__ Wl, const float* __restrict__ Wr,
    const float* __restrict__ bias, const float* __restrict__ gamma,
    const float* __restrict__ beta, const float* __restrict__ rmean,
    const float* __restrict__ rvar, float* __restrict__ hout, int n) {
  __shared__ float As[64][HID];
  __shared__ float Hs[64][HID];
  int tid = threadIdx.x;
  int node0 = blockIdx.x * 64;
#pragma unroll
  for (int it = 0; it < 8; ++it) {
    int idx = it * 256 + tid;       // float4 index over 64x128
    int row = idx >> 5;
    int c4 = (idx & 31) << 2;
    int node = node0 + row;
    float4 av = make_float4(0.f, 0.f, 0.f, 0.f);
    float4 hv = make_float4(0.f, 0.f, 0.f, 0.f);
    if (node < n) {
      av = *(const float4*)(agg + ((size_t)node << 7) + c4);
      hv = *(const float4*)(hin + ((size_t)node << 7) + c4);
    }
    *(float4*)&As[row][c4] = av;
    *(float4*)&Hs[row][c4] = hv;
  }
  __syncthreads();

  int tx = tid & 31;
  int ty = tid >> 5;
  int c0 = tx << 2;
  float4 acc[8];
#pragma unroll
  for (int r = 0; r < 8; ++r) acc[r] = make_float4(0.f, 0.f, 0.f, 0.f);

  for (int k = 0; k < HID; k += 4) {
    float4 wl[4], wr[4];
#pragma unroll
    for (int kk = 0; kk < 4; ++kk) {
      wl[kk] = *(const float4*)(Wl + (size_t)(k + kk) * HID + c0);
      wr[kk] = *(const float4*)(Wr + (size_t)(k + kk) * HID + c0);
    }
#pragma unroll
    for (int r = 0; r < 8; ++r) {
      int row = ty + (r << 3);
      float4 a = *(const float4*)&As[row][k];
      float4 hh = *(const float4*)&Hs[row][k];
      acc[r].x += a.x * wl[0].x + a.y * wl[1].x + a.z * wl[2].x + a.w * wl[3].x
                + hh.x * wr[0].x + hh.y * wr[1].x + hh.z * wr[2].x + hh.w * wr[3].x;
      acc[r].y += a.x * wl[0].y + a.y * wl[1].y + a.z * wl[2].y + a.w * wl[3].y
                + hh.x * wr[0].y + hh.y * wr[1].y + hh.z * wr[2].y + hh.w * wr[3].y;
      acc[r].z += a.x * wl[0].z + a.y * wl[1].z + a.z * wl[2].z + a.w * wl[3].z
                + hh.x * wr[0].z + hh.y * wr[1].z + hh.z * wr[2].z + hh.w * wr[3].z;
      acc[r].w += a.x * wl[0].w + a.y * wl[1].w + a.z * wl[2].w + a.w * wl[3].w
                + hh.x * wr[0].w + hh.y * wr[1].w + hh.z * wr[2].w + hh.w * wr[3].w;
    }
  }

  float4 g4 = *(const float4*)(gamma + c0);
  float4 be4 = *(const float4*)(beta + c0);
  float4 rm4 = *(const float4*)(rmean + c0);
  float4 rv4 = *(const float4*)(rvar + c0);
  float4 b4 = *(const float4*)(bias + c0);
  float sx = g4.x * rsqrtf(rv4.x + BN_EPS); float shx = be4.x - rm4.x * sx;
  float sy = g4.y * rsqrtf(rv4.y + BN_EPS); float shy = be4.y - rm4.y * sy;
  float sz = g4.z * rsqrtf(rv4.z + BN_EPS); float shz = be4.z - rm4.z * sz;
  float sw = g4.w * rsqrtf(rv4.w + BN_EPS); float shw = be4.w - rm4.w * sw;

#pragma unroll
  for (int r = 0; r < 8; ++r) {
    int node = node0 + ty + (r << 3);
    if (node < n) {
      float4 o;
      o.x = fmaxf((acc[r].x + b4.x) * sx + shx, 0.f);
      o.y = fmaxf((acc[r].y + b4.y) * sy + shy, 0.f);
      o.z = fmaxf((acc[r].z + b4.z) * sz + shz, 0.f);
      o.w = fmaxf((acc[r].w + b4.w) * sw + shw, 0.f);
      *(float4*)(hout + ((size_t)node << 7) + c0) = o;
    }
  }
}

// ---------------- final layer: project to 2ch first (linearity), then spmm ----------------

__global__ void k_pq(const float* __restrict__ h, const float* __restrict__ Wl_out,
                     const float* __restrict__ Wr_out, float* __restrict__ p,
                     float* __restrict__ q, int n) {
  int node = blockIdx.x * 4 + (threadIdx.x >> 6);
  if (node >= n) return;
  int lane = threadIdx.x & 63;
  float2 hv = *(const float2*)(h + ((size_t)node << 7) + (lane << 1));
  float4 wl = *(const float4*)(Wl_out + (lane << 2)); // rows 2l,2l+1; cols 0,1
  float4 wr = *(const float4*)(Wr_out + (lane << 2));
  float p0 = hv.x * wl.x + hv.y * wl.z;
  float p1 = hv.x * wl.y + hv.y * wl.w;
  float q0 = hv.x * wr.x + hv.y * wr.z;
  float q1 = hv.x * wr.y + hv.y * wr.w;
#pragma unroll
  for (int off = 32; off > 0; off >>= 1) {
    p0 += __shfl_xor(p0, off, 64);
    p1 += __shfl_xor(p1, off, 64);
    q0 += __shfl_xor(q0, off, 64);
    q1 += __shfl_xor(q1, off, 64);
  }
  if (lane == 0) {
    *(float2*)(p + (size_t)node * 2) = make_float2(p0, p1);
    *(float2*)(q + (size_t)node * 2) = make_float2(q0, q1);
  }
}

__global__ void k_spmm2(const float* __restrict__ p, const float* __restrict__ q,
                        const int* __restrict__ row_ptr, const int* __restrict__ col,
                        const float* __restrict__ inv_deg, const float* __restrict__ b_out,
                        float* __restrict__ out_node, int n) {
  int i = blockIdx.x * blockDim.x + threadIdx.x;
  if (i >= n) return;
  int beg = row_ptr[i], end = row_ptr[i + 1];
  float a0 = 0.f, a1 = 0.f;
  for (int e = beg; e < end; ++e) {
    int s = col[e];
    float2 v = *(const float2*)(p + (size_t)s * 2);
    a0 += v.x; a1 += v.y;
  }
  float w = inv_deg[i];
  float2 qv = *(const float2*)(q + (size_t)i * 2);
  out_node[(size_t)i * 2] = a0 * w + qv.x + b_out[0];
  out_node[(size_t)i * 2 + 1] = a1 * w + qv.y + b_out[1];
}

__global__ void k_pool(const float* __restrict__ out_node, const int* __restrict__ batch,
                       float* __restrict__ out, float* __restrict__ gcnt, int n) {
  int i = blockIdx.x * blockDim.x + threadIdx.x;
  if (i >= n) return;
  int g = batch[i];
  atomicAdd(&out[g * 2], out_node[(size_t)i * 2]);
  atomicAdd(&out[g * 2 + 1], out_node[(size_t)i * 2 + 1]);
  atomicAdd(&gcnt[g], 1.0f);
}

__global__ void k_div(float* __restrict__ out, const float* __restrict__ gcnt, int ng) {
  int i = blockIdx.x * blockDim.x + threadIdx.x;
  if (i < ng * 2) out[i] /= fmaxf(gcnt[i >> 1], 1.0f);
}

// ---------------- launch ----------------

extern "C" void kernel_launch(void* const* d_in, const int* in_sizes, int n_in,
                              void* d_out, int out_size, void* d_ws, size_t ws_size,
                              hipStream_t stream) {
  const float* x = (const float*)d_in[0];
  const float* Wl = (const float*)d_in[1];
  const float* Wr = (const float*)d_in[2];
  const float* b = (const float*)d_in[3];
  const float* gamma = (const float*)d_in[4];
  const float* beta = (const float*)d_in[5];
  const float* rmean = (const float*)d_in[6];
  const float* rvar = (const float*)d_in[7];
  const float* Wl_out = (const float*)d_in[8];
  const float* Wr_out = (const float*)d_in[9];
  const float* b_out = (const float*)d_in[10];
  const int* eidx = (const int*)d_in[11];
  const int* batch = (const int*)d_in[12];

  const int N = in_sizes[0] / HID;
  const int E = in_sizes[11] / 2;
  const int L = in_sizes[1] / (HID * HID);
  const int NG = out_size / 2;
  const int* src = eidx;
  const int* dst = eidx + E;

  char* ws = (char*)d_ws;
  size_t off = 0;
  auto alloc = [&](size_t bytes) {
    void* ptr = ws + off;
    off += (bytes + 255) & ~(size_t)255;
    return ptr;
  };
  int* row_ptr = (int*)alloc((size_t)(N + 1) * 4);
  int* cursor = (int*)alloc((size_t)N * 4);
  int* col = (int*)alloc((size_t)E * 4);
  float* inv_deg = (float*)alloc((size_t)N * 4);
  float* h = (float*)alloc((size_t)N * HID * 4);
  float* agg = (float*)alloc((size_t)N * HID * 4);
  float* p = (float*)alloc((size_t)N * 2 * 4);
  float* q = (float*)alloc((size_t)N * 2 * 4);
  float* gcnt = (float*)alloc((size_t)NG * 4);
  float* out_node = agg;  // agg is free by the time spmm2 runs

  hipMemsetAsync(cursor, 0, (size_t)N * 4, stream);
  k_count<<<(E + 255) / 256, 256, 0, stream>>>(dst, cursor, E);
  k_scan<<<1, 1024, 0, stream>>>(cursor, row_ptr, N);
  k_invdeg<<<(N + 255) / 256, 256, 0, stream>>>(row_ptr, inv_deg, N);
  k_fill<<<(E + 255) / 256, 256, 0, stream>>>(src, dst, cursor, col, E);

  const float* hin = x;
  for (int l = 0; l < L; ++l) {
    k_spmm<<<(N + 3) / 4, 256, 0, stream>>>(hin, row_ptr, col, inv_deg, agg, N);
    k_dense<<<(N + 63) / 64, 256, 0, stream>>>(
        hin, agg, Wl + (size_t)l * HID * HID, Wr + (size_t)l * HID * HID,
        b + (size_t)l * HID, gamma + (size_t)l * HID, beta + (size_t)l * HID,
        rmean + (size_t)l * HID, rvar + (size_t)l * HID, h, N);
    hin = h;
  }
  k_pq<<<(N + 3) / 4, 256, 0, stream>>>(hin, Wl_out, Wr_out, p, q, N);
  k_spmm2<<<(N + 255) / 256, 256, 0, stream>>>(p, q, row_ptr, col, inv_deg, b_out, out_node, N);
  hipMemsetAsync(d_out, 0, (size_t)out_size * 4, stream);
  hipMemsetAsync(gcnt, 0, (size_t)NG * 4, stream);
  k_pool<<<(N + 255) / 256, 256, 0, stream>>>(out_node, batch, (float*)d_out, gcnt, N);
  k_div<<<(NG * 2 + 255) / 256, 256, 0, stream>>>((float*)d_out, gcnt, NG);
}

// Round 2
// 990.208 us; speedup vs baseline: 1.4274x; 1.4274x over previous
//
#include <hip/hip_runtime.h>

#define HID 128
#define BN_EPS 1e-5f

__device__ inline unsigned short f2b(float f) {  // f32 -> bf16 RNE
  unsigned int u = __float_as_uint(f);
  unsigned int r = (u + 0x7fffu + ((u >> 16) & 1u)) >> 16;
  return (unsigned short)r;
}

// ---------------- CSR build ----------------

__global__ void k_count(const int* __restrict__ dst, int* __restrict__ cnt, int e) {
  int i = blockIdx.x * blockDim.x + threadIdx.x;
  if (i < e) atomicAdd(&cnt[dst[i]], 1);
}

// single-block hierarchical exclusive scan: cursor(deg in) -> row_ptr, cursor(excl out)
__global__ void k_scan(int* __restrict__ cursor, int* __restrict__ row_ptr, int n) {
  __shared__ int wsum[16];
  __shared__ int wincl[16];
  __shared__ int s_carry;
  int tid = threadIdx.x;
  int lane = tid & 63;
  int wid = tid >> 6;
  if (tid == 0) s_carry = 0;
  __syncthreads();
  for (int base = 0; base < n; base += 1024) {
    int i = base + tid;
    int v = (i < n) ? cursor[i] : 0;
    int x = v;
#pragma unroll
    for (int off = 1; off < 64; off <<= 1) {
      int y = __shfl_up(x, off, 64);
      if (lane >= off) x += y;
    }
    if (lane == 63) wsum[wid] = x;
    __syncthreads();
    if (wid == 0) {
      int s = (lane < 16) ? wsum[lane] : 0;
#pragma unroll
      for (int off = 1; off < 16; off <<= 1) {
        int y = __shfl_up(s, off, 64);
        if (lane >= off) s += y;
      }
      if (lane < 16) wincl[lane] = s;
    }
    __syncthreads();
    int carry = s_carry;
    int woff = (wid == 0) ? 0 : wincl[wid - 1];
    int excl = carry + woff + (x - v);
    if (i < n) { row_ptr[i] = excl; cursor[i] = excl; }
    __syncthreads();
    if (tid == 0) s_carry = carry + wincl[15];
    __syncthreads();
  }
  if (tid == 0) row_ptr[n] = s_carry;
}

__global__ void k_invdeg(const int* __restrict__ row_ptr, float* __restrict__ inv_deg, int n) {
  int i = blockIdx.x * blockDim.x + threadIdx.x;
  if (i < n) {
    int d = row_ptr[i + 1] - row_ptr[i];
    inv_deg[i] = 1.0f / (float)max(d, 1);
  }
}

__global__ void k_fill(const int* __restrict__ src, const int* __restrict__ dst,
                       int* __restrict__ cursor, int* __restrict__ col, int e) {
  int i = blockIdx.x * blockDim.x + threadIdx.x;
  if (i < e) {
    int d = dst[i];
    int pos = atomicAdd(&cursor[d], 1);
    col[pos] = src[i];
  }
}

// ---------------- x (f32) -> bf16 shadow ----------------

__global__ void k_x2b(const float* __restrict__ x, unsigned short* __restrict__ xb, int n4) {
  int i = blockIdx.x * blockDim.x + threadIdx.x;
  if (i < n4) {
    float4 v = ((const float4*)x)[i];
    unsigned int lo = (unsigned int)f2b(v.x) | ((unsigned int)f2b(v.y) << 16);
    unsigned int hi = (unsigned int)f2b(v.z) | ((unsigned int)f2b(v.w) << 16);
    ((uint2*)xb)[i] = make_uint2(lo, hi);
  }
}

// ---------------- SpMM: agg[i] = inv_deg[i] * sum_{j in N(i)} hb[j]  (bf16 gather, f32 acc)
// one 64-lane wave per node, 2 channels/lane, edges unrolled x4 for MLP

__global__ void k_spmm(const unsigned short* __restrict__ hb, const int* __restrict__ row_ptr,
                       const int* __restrict__ col, const float* __restrict__ inv_deg,
                       float* __restrict__ agg, int n) {
  int node = blockIdx.x * 4 + (threadIdx.x >> 6);
  if (node >= n) return;
  int lane = threadIdx.x & 63;
  int beg = row_ptr[node], end = row_ptr[node + 1];
  float ax0 = 0.f, ay0 = 0.f, ax1 = 0.f, ay1 = 0.f;
  float ax2 = 0.f, ay2 = 0.f, ax3 = 0.f, ay3 = 0.f;
  const unsigned short* base = hb + (lane << 1);
  int e = beg;
  for (; e + 4 <= end; e += 4) {
    int s0 = col[e], s1 = col[e + 1], s2 = col[e + 2], s3 = col[e + 3];
    unsigned int v0 = *(const unsigned int*)(base + ((size_t)s0 << 7));
    unsigned int v1 = *(const unsigned int*)(base + ((size_t)s1 << 7));
    unsigned int v2 = *(const unsigned int*)(base + ((size_t)s2 << 7));
    unsigned int v3 = *(const unsigned int*)(base + ((size_t)s3 << 7));
    ax0 += __uint_as_float(v0 << 16); ay0 += __uint_as_float(v0 & 0xffff0000u);
    ax1 += __uint_as_float(v1 << 16); ay1 += __uint_as_float(v1 & 0xffff0000u);
    ax2 += __uint_as_float(v2 << 16); ay2 += __uint_as_float(v2 & 0xffff0000u);
    ax3 += __uint_as_float(v3 << 16); ay3 += __uint_as_float(v3 & 0xffff0000u);
  }
  for (; e < end; ++e) {
    int s = col[e];
    unsigned int v = *(const unsigned int*)(base + ((size_t)s << 7));
    ax0 += __uint_as_float(v << 16); ay0 += __uint_as_float(v & 0xffff0000u);
  }
  float ax = (ax0 + ax1) + (ax2 + ax3);
  float ay = (ay0 + ay1) + (ay2 + ay3);
  float w = inv_deg[node];
  *(float2*)(agg + ((size_t)node << 7) + (lane << 1)) = make_float2(ax * w, ay * w);
}

// ---------------- dense: h_out = relu(bn(agg@Wl + h@Wr + b)), also emits bf16 copy

__global__ __launch_bounds__(256) void k_dense(
    const float* __restrict__ hin, const float* __restrict__ agg,
    const float* __restrict__ Wl, const float* __restrict__ Wr,
    const float* __restrict__ bias, const float* __restrict__ gamma,
    const float* __restrict__ beta, const float* __restrict__ rmean,
    const float* __restrict__ rvar, float* __restrict__ hout,
    unsigned short* __restrict__ hbout, int n) {
  __shared__ float As[64][HID];
  __shared__ float Hs[64][HID];
  int tid = threadIdx.x;
  int node0 = blockIdx.x * 64;
#pragma unroll
  for (int it = 0; it < 8; ++it) {
    int idx = it * 256 + tid;       // float4 index over 64x128
    int row = idx >> 5;
    int c4 = (idx & 31) << 2;
    int node = node0 + row;
    float4 av = make_float4(0.f, 0.f, 0.f, 0.f);
    float4 hv = make_float4(0.f, 0.f, 0.f, 0.f);
    if (node < n) {
      av = *(const float4*)(agg + ((size_t)node << 7) + c4);
      hv = *(const float4*)(hin + ((size_t)node << 7) + c4);
    }
    *(float4*)&As[row][c4] = av;
    *(float4*)&Hs[row][c4] = hv;
  }
  __syncthreads();

  int tx = tid & 31;
  int ty = tid >> 5;
  int c0 = tx << 2;
  float4 acc[8];
#pragma unroll
  for (int r = 0; r < 8; ++r) acc[r] = make_float4(0.f, 0.f, 0.f, 0.f);

  for (int k = 0; k < HID; k += 4) {
    float4 wl[4], wr[4];
#pragma unroll
    for (int kk = 0; kk < 4; ++kk) {
      wl[kk] = *(const float4*)(Wl + (size_t)(k + kk) * HID + c0);
      wr[kk] = *(const float4*)(Wr + (size_t)(k + kk) * HID + c0);
    }
#pragma unroll
    for (int r = 0; r < 8; ++r) {
      int row = ty + (r << 3);
      float4 a = *(const float4*)&As[row][k];
      float4 hh = *(const float4*)&Hs[row][k];
      acc[r].x += a.x * wl[0].x + a.y * wl[1].x + a.z * wl[2].x + a.w * wl[3].x
                + hh.x * wr[0].x + hh.y * wr[1].x + hh.z * wr[2].x + hh.w * wr[3].x;
      acc[r].y += a.x * wl[0].y + a.y * wl[1].y + a.z * wl[2].y + a.w * wl[3].y
                + hh.x * wr[0].y + hh.y * wr[1].y + hh.z * wr[2].y + hh.w * wr[3].y;
      acc[r].z += a.x * wl[0].z + a.y * wl[1].z + a.z * wl[2].z + a.w * wl[3].z
                + hh.x * wr[0].z + hh.y * wr[1].z + hh.z * wr[2].z + hh.w * wr[3].z;
      acc[r].w += a.x * wl[0].w + a.y * wl[1].w + a.z * wl[2].w + a.w * wl[3].w
                + hh.x * wr[0].w + hh.y * wr[1].w + hh.z * wr[2].w + hh.w * wr[3].w;
    }
  }

  float4 g4 = *(const float4*)(gamma + c0);
  float4 be4 = *(const float4*)(beta + c0);
  float4 rm4 = *(const float4*)(rmean + c0);
  float4 rv4 = *(const float4*)(rvar + c0);
  float4 b4 = *(const float4*)(bias + c0);
  float sx = g4.x * rsqrtf(rv4.x + BN_EPS); float shx = be4.x - rm4.x * sx;
  float sy = g4.y * rsqrtf(rv4.y + BN_EPS); float shy = be4.y - rm4.y * sy;
  float sz = g4.z * rsqrtf(rv4.z + BN_EPS); float shz = be4.z - rm4.z * sz;
  float sw = g4.w * rsqrtf(rv4.w + BN_EPS); float shw = be4.w - rm4.w * sw;

#pragma unroll
  for (int r = 0; r < 8; ++r) {
    int node = node0 + ty + (r << 3);
    if (node < n) {
      float4 o;
      o.x = fmaxf((acc[r].x + b4.x) * sx + shx, 0.f);
      o.y = fmaxf((acc[r].y + b4.y) * sy + shy, 0.f);
      o.z = fmaxf((acc[r].z + b4.z) * sz + shz, 0.f);
      o.w = fmaxf((acc[r].w + b4.w) * sw + shw, 0.f);
      *(float4*)(hout + ((size_t)node << 7) + c0) = o;
      ushort4 ob;
      ob.x = f2b(o.x); ob.y = f2b(o.y); ob.z = f2b(o.z); ob.w = f2b(o.w);
      *(ushort4*)(hbout + ((size_t)node << 7) + c0) = ob;
    }
  }
}

// ---------------- final layer: project to 2ch first (linearity), then spmm ----------------

__global__ void k_pq(const float* __restrict__ h, const float* __restrict__ Wl_out,
                     const float* __restrict__ Wr_out, float* __restrict__ p,
                     float* __restrict__ q, int n) {
  int node = blockIdx.x * 4 + (threadIdx.x >> 6);
  if (node >= n) return;
  int lane = threadIdx.x & 63;
  float2 hv = *(const float2*)(h + ((size_t)node << 7) + (lane << 1));
  float4 wl = *(const float4*)(Wl_out + (lane << 2)); // rows 2l,2l+1; cols 0,1
  float4 wr = *(const float4*)(Wr_out + (lane << 2));
  float p0 = hv.x * wl.x + hv.y * wl.z;
  float p1 = hv.x * wl.y + hv.y * wl.w;
  float q0 = hv.x * wr.x + hv.y * wr.z;
  float q1 = hv.x * wr.y + hv.y * wr.w;
#pragma unroll
  for (int off = 32; off > 0; off >>= 1) {
    p0 += __shfl_xor(p0, off, 64);
    p1 += __shfl_xor(p1, off, 64);
    q0 += __shfl_xor(q0, off, 64);
    q1 += __shfl_xor(q1, off, 64);
  }
  if (lane == 0) {
    *(float2*)(p + (size_t)node * 2) = make_float2(p0, p1);
    *(float2*)(q + (size_t)node * 2) = make_float2(q0, q1);
  }
}

__global__ void k_spmm2(const float* __restrict__ p, const float* __restrict__ q,
                        const int* __restrict__ row_ptr, const int* __restrict__ col,
                        const float* __restrict__ inv_deg, const float* __restrict__ b_out,
                        float* __restrict__ out_node, int n) {
  int i = blockIdx.x * blockDim.x + threadIdx.x;
  if (i >= n) return;
  int beg = row_ptr[i], end = row_ptr[i + 1];
  float a0 = 0.f, a1 = 0.f;
  for (int e = beg; e < end; ++e) {
    int s = col[e];
    float2 v = *(const float2*)(p + (size_t)s * 2);
    a0 += v.x; a1 += v.y;
  }
  float w = inv_deg[i];
  float2 qv = *(const float2*)(q + (size_t)i * 2);
  out_node[(size_t)i * 2] = a0 * w + qv.x + b_out[0];
  out_node[(size_t)i * 2 + 1] = a1 * w + qv.y + b_out[1];
}

__global__ void k_pool(const float* __restrict__ out_node, const int* __restrict__ batch,
                       float* __restrict__ out, float* __restrict__ gcnt, int n) {
  int i = blockIdx.x * blockDim.x + threadIdx.x;
  if (i >= n) return;
  int g = batch[i];
  atomicAdd(&out[g * 2], out_node[(size_t)i * 2]);
  atomicAdd(&out[g * 2 + 1], out_node[(size_t)i * 2 + 1]);
  atomicAdd(&gcnt[g], 1.0f);
}

__global__ void k_div(float* __restrict__ out, const float* __restrict__ gcnt, int ng) {
  int i = blockIdx.x * blockDim.x + threadIdx.x;
  if (i < ng * 2) out[i] /= fmaxf(gcnt[i >> 1], 1.0f);
}

// ---------------- launch ----------------

extern "C" void kernel_launch(void* const* d_in, const int* in_sizes, int n_in,
                              void* d_out, int out_size, void* d_ws, size_t ws_size,
                              hipStream_t stream) {
  const float* x = (const float*)d_in[0];
  const float* Wl = (const float*)d_in[1];
  const float* Wr = (const float*)d_in[2];
  const float* b = (const float*)d_in[3];
  const float* gamma = (const float*)d_in[4];
  const float* beta = (const float*)d_in[5];
  const float* rmean = (const float*)d_in[6];
  const float* rvar = (const float*)d_in[7];
  const float* Wl_out = (const float*)d_in[8];
  const float* Wr_out = (const float*)d_in[9];
  const float* b_out = (const float*)d_in[10];
  const int* eidx = (const int*)d_in[11];
  const int* batch = (const int*)d_in[12];

  const int N = in_sizes[0] / HID;
  const int E = in_sizes[11] / 2;
  const int L = in_sizes[1] / (HID * HID);
  const int NG = out_size / 2;
  const int* src = eidx;
  const int* dst = eidx + E;

  char* ws = (char*)d_ws;
  size_t off = 0;
  auto alloc = [&](size_t bytes) {
    void* ptr = ws + off;
    off += (bytes + 255) & ~(size_t)255;
    return ptr;
  };
  int* row_ptr = (int*)alloc((size_t)(N + 1) * 4);
  int* cursor = (int*)alloc((size_t)N * 4);
  int* col = (int*)alloc((size_t)E * 4);
  float* inv_deg = (float*)alloc((size_t)N * 4);
  float* h = (float*)alloc((size_t)N * HID * 4);
  float* agg = (float*)alloc((size_t)N * HID * 4);
  unsigned short* hb = (unsigned short*)alloc((size_t)N * HID * 2);
  float* p = (float*)alloc((size_t)N * 2 * 4);
  float* q = (float*)alloc((size_t)N * 2 * 4);
  float* gcnt = (float*)alloc((size_t)NG * 4);
  float* out_node = agg;  // agg is free by the time spmm2 runs

  hipMemsetAsync(cursor, 0, (size_t)N * 4, stream);
  k_count<<<(E + 255) / 256, 256, 0, stream>>>(dst, cursor, E);
  k_scan<<<1, 1024, 0, stream>>>(cursor, row_ptr, N);
  k_invdeg<<<(N + 255) / 256, 256, 0, stream>>>(row_ptr, inv_deg, N);
  k_fill<<<(E + 255) / 256, 256, 0, stream>>>(src, dst, cursor, col, E);
  k_x2b<<<(N * HID / 4 + 255) / 256, 256, 0, stream>>>(x, hb, N * HID / 4);

  const float* hin = x;
  for (int l = 0; l < L; ++l) {
    k_spmm<<<(N + 3) / 4, 256, 0, stream>>>(hb, row_ptr, col, inv_deg, agg, N);
    k_dense<<<(N + 63) / 64, 256, 0, stream>>>(
        hin, agg, Wl + (size_t)l * HID * HID, Wr + (size_t)l * HID * HID,
        b + (size_t)l * HID, gamma + (size_t)l * HID, beta + (size_t)l * HID,
        rmean + (size_t)l * HID, rvar + (size_t)l * HID, h, hb, N);
    hin = h;
  }
  k_pq<<<(N + 3) / 4, 256, 0, stream>>>(hin, Wl_out, Wr_out, p, q, N);
  k_spmm2<<<(N + 255) / 256, 256, 0, stream>>>(p, q, row_ptr, col, inv_deg, b_out, out_node, N);
  hipMemsetAsync(d_out, 0, (size_t)out_size * 4, stream);
  hipMemsetAsync(gcnt, 0, (size_t)NG * 4, stream);
  k_pool<<<(N + 255) / 256, 256, 0, stream>>>(out_node, batch, (float*)d_out, gcnt, N);
  k_div<<<(NG * 2 + 255) / 256, 256, 0, stream>>>((float*)d_out, gcnt, NG);
}

// Round 3
// 853.995 us; speedup vs baseline: 1.6550x; 1.1595x over previous
//
#include <hip/hip_runtime.h>

#define HID 128
#define BN_EPS 1e-5f

typedef short bf16x8 __attribute__((ext_vector_type(8)));
typedef float f32x4 __attribute__((ext_vector_type(4)));

__device__ inline unsigned short f2b(float f) {  // f32 -> bf16 RNE
  unsigned int u = __float_as_uint(f);
  unsigned int r = (u + 0x7fffu + ((u >> 16) & 1u)) >> 16;
  return (unsigned short)r;
}
__device__ inline float bl(unsigned int v) { return __uint_as_float(v << 16); }
__device__ inline float bh(unsigned int v) { return __uint_as_float(v & 0xffff0000u); }

// ---------------- CSR build ----------------

__global__ void k_count(const int* __restrict__ dst, int* __restrict__ cnt, int e) {
  int i = (blockIdx.x * blockDim.x + threadIdx.x) * 4;
  if (i + 4 <= e) {
    int d0 = dst[i], d1 = dst[i + 1], d2 = dst[i + 2], d3 = dst[i + 3];
    atomicAdd(&cnt[d0], 1); atomicAdd(&cnt[d1], 1);
    atomicAdd(&cnt[d2], 1); atomicAdd(&cnt[d3], 1);
  } else {
    for (; i < e; ++i) atomicAdd(&cnt[dst[i]], 1);
  }
}

// single-block hierarchical exclusive scan: cursor(deg in) -> row_ptr, cursor(excl out)
__global__ void k_scan(int* __restrict__ cursor, int* __restrict__ row_ptr, int n) {
  __shared__ int wsum[16];
  __shared__ int wincl[16];
  __shared__ int s_carry;
  int tid = threadIdx.x;
  int lane = tid & 63;
  int wid = tid >> 6;
  if (tid == 0) s_carry = 0;
  __syncthreads();
  for (int base = 0; base < n; base += 1024) {
    int i = base + tid;
    int v = (i < n) ? cursor[i] : 0;
    int x = v;
#pragma unroll
    for (int off = 1; off < 64; off <<= 1) {
      int y = __shfl_up(x, off, 64);
      if (lane >= off) x += y;
    }
    if (lane == 63) wsum[wid] = x;
    __syncthreads();
    if (wid == 0) {
      int s = (lane < 16) ? wsum[lane] : 0;
#pragma unroll
      for (int off = 1; off < 16; off <<= 1) {
        int y = __shfl_up(s, off, 64);
        if (lane >= off) s += y;
      }
      if (lane < 16) wincl[lane] = s;
    }
    __syncthreads();
    int carry = s_carry;
    int woff = (wid == 0) ? 0 : wincl[wid - 1];
    int excl = carry + woff + (x - v);
    if (i < n) { row_ptr[i] = excl; cursor[i] = excl; }
    __syncthreads();
    if (tid == 0) s_carry = carry + wincl[15];
    __syncthreads();
  }
  if (tid == 0) row_ptr[n] = s_carry;
}

__global__ void k_invdeg(const int* __restrict__ row_ptr, float* __restrict__ inv_deg, int n) {
  int i = blockIdx.x * blockDim.x + threadIdx.x;
  if (i < n) {
    int d = row_ptr[i + 1] - row_ptr[i];
    inv_deg[i] = 1.0f / (float)max(d, 1);
  }
}

__global__ void k_fill(const int* __restrict__ src, const int* __restrict__ dst,
                       int* __restrict__ cursor, int* __restrict__ col, int e) {
  int i = (blockIdx.x * blockDim.x + threadIdx.x) * 4;
  if (i + 4 <= e) {
    int d0 = dst[i], d1 = dst[i + 1], d2 = dst[i + 2], d3 = dst[i + 3];
    int s0 = src[i], s1 = src[i + 1], s2 = src[i + 2], s3 = src[i + 3];
    int p0 = atomicAdd(&cursor[d0], 1);
    int p1 = atomicAdd(&cursor[d1], 1);
    int p2 = atomicAdd(&cursor[d2], 1);
    int p3 = atomicAdd(&cursor[d3], 1);
    col[p0] = s0; col[p1] = s1; col[p2] = s2; col[p3] = s3;
  } else {
    for (; i < e; ++i) {
      int pos = atomicAdd(&cursor[dst[i]], 1);
      col[pos] = src[i];
    }
  }
}

// ---------------- small prep ----------------

__global__ void k_x2b(const float* __restrict__ x, unsigned short* __restrict__ xb, int n4) {
  int i = blockIdx.x * blockDim.x + threadIdx.x;
  if (i < n4) {
    float4 v = ((const float4*)x)[i];
    unsigned int lo = (unsigned int)f2b(v.x) | ((unsigned int)f2b(v.y) << 16);
    unsigned int hi = (unsigned int)f2b(v.z) | ((unsigned int)f2b(v.w) << 16);
    ((uint2*)xb)[i] = make_uint2(lo, hi);
  }
}

// W [nmats][128][128] (k-major) -> Wt [nmats][128][128] bf16 ([out_ch][k])
__global__ void k_wconv(const float* __restrict__ W, unsigned short* __restrict__ Wt, int total) {
  int i = blockIdx.x * blockDim.x + threadIdx.x;
  if (i < total) {
    int mat = i >> 14, rem = i & 16383, nn = rem >> 7, kk = rem & 127;
    Wt[i] = f2b(W[(mat << 14) + (kk << 7) + nn]);
  }
}

__global__ void k_bnprep(const float* __restrict__ g, const float* __restrict__ be,
                         const float* __restrict__ rm, const float* __restrict__ rv,
                         float* __restrict__ sc, float* __restrict__ sh, int n) {
  int i = blockIdx.x * blockDim.x + threadIdx.x;
  if (i < n) {
    float s = g[i] * rsqrtf(rv[i] + BN_EPS);
    sc[i] = s;
    sh[i] = be[i] - rm[i] * s;
  }
}

// ---------------- MFMA dense: u = h@Wl (bf16), r = h@Wr + b (f32) ----------------
// swapped operands: A = Wt[ch][k], B = hb viewed as [k][node]; D[ch][node].
// block = 256 thr = 4 waves; block covers 64 nodes; wave w -> nodes w*16..w*16+15.

__global__ __launch_bounds__(256) void k_gemm(
    const unsigned short* __restrict__ hb,   // [n][128] bf16
    const unsigned short* __restrict__ Wlt,  // [128][128] bf16 [out_ch][k]
    const unsigned short* __restrict__ Wrt,
    const float* __restrict__ bias,          // [128]
    unsigned short* __restrict__ u,          // [n][128] bf16
    float* __restrict__ r,                   // [n][128] f32
    int n) {
  int wid = threadIdx.x >> 6;
  int lane = threadIdx.x & 63;
  int l15 = lane & 15, lhi = lane >> 4;
  int node = blockIdx.x * 64 + wid * 16 + l15;
  int nsafe = node < n ? node : 0;
  const unsigned short* hrow = hb + ((size_t)nsafe << 7) + (lhi << 3);
  const unsigned short* wlp = Wlt + (l15 << 7) + (lhi << 3);
  const unsigned short* wrp = Wrt + (l15 << 7) + (lhi << 3);

  f32x4 accU[8], accR[8];
#pragma unroll
  for (int m = 0; m < 8; ++m) { accU[m] = (f32x4)(0.f); accR[m] = (f32x4)(0.f); }

#pragma unroll
  for (int ks = 0; ks < 4; ++ks) {
    bf16x8 bfrag = *(const bf16x8*)(hrow + ks * 32);
#pragma unroll
    for (int m = 0; m < 8; ++m) {
      bf16x8 al = *(const bf16x8*)(wlp + m * 16 * 128 + ks * 32);
      accU[m] = __builtin_amdgcn_mfma_f32_16x16x32_bf16(al, bfrag, accU[m], 0, 0, 0);
      bf16x8 ar = *(const bf16x8*)(wrp + m * 16 * 128 + ks * 32);
      accR[m] = __builtin_amdgcn_mfma_f32_16x16x32_bf16(ar, bfrag, accR[m], 0, 0, 0);
    }
  }

  if (node < n) {
#pragma unroll
    for (int m = 0; m < 8; ++m) {
      int ch = m * 16 + (lhi << 2);  // 4 consecutive channels
      unsigned int lo = (unsigned int)f2b(accU[m][0]) | ((unsigned int)f2b(accU[m][1]) << 16);
      unsigned int hi = (unsigned int)f2b(accU[m][2]) | ((unsigned int)f2b(accU[m][3]) << 16);
      *(uint2*)(u + ((size_t)node << 7) + ch) = make_uint2(lo, hi);
      float4 bi = *(const float4*)(bias + ch);
      *(float4*)(r + ((size_t)node << 7) + ch) =
          make_float4(accR[m][0] + bi.x, accR[m][1] + bi.y, accR[m][2] + bi.z, accR[m][3] + bi.w);
    }
  }
}

// ---------------- fused SpMM: hb_out = relu(bn(mean-gather(u) + r)) ----------------
// wave per node: 4 edge-slots x 16 channel-lanes (8 ch each, 16B gathers)

__global__ __launch_bounds__(256) void k_spmm_f(
    const unsigned short* __restrict__ u, const float* __restrict__ r,
    const int* __restrict__ row_ptr, const int* __restrict__ col,
    const float* __restrict__ inv_deg, const float* __restrict__ sc,
    const float* __restrict__ sh, unsigned short* __restrict__ hbo, int n) {
  int node = blockIdx.x * 4 + (threadIdx.x >> 6);
  if (node >= n) return;
  int lane = threadIdx.x & 63;
  int slot = lane >> 4, c16 = lane & 15;
  int beg = row_ptr[node], end = row_ptr[node + 1];
  float a0 = 0, a1 = 0, a2 = 0, a3 = 0, a4 = 0, a5 = 0, a6 = 0, a7 = 0;
  const unsigned short* base = u + (c16 << 3);
  int e = beg;
  for (; e + 8 <= end; e += 8) {
    int s0 = col[e + slot];
    int s1 = col[e + 4 + slot];
    uint4 v0 = *(const uint4*)(base + ((size_t)s0 << 7));
    uint4 v1 = *(const uint4*)(base + ((size_t)s1 << 7));
    a0 += bl(v0.x); a1 += bh(v0.x); a2 += bl(v0.y); a3 += bh(v0.y);
    a4 += bl(v0.z); a5 += bh(v0.z); a6 += bl(v0.w); a7 += bh(v0.w);
    a0 += bl(v1.x); a1 += bh(v1.x); a2 += bl(v1.y); a3 += bh(v1.y);
    a4 += bl(v1.z); a5 += bh(v1.z); a6 += bl(v1.w); a7 += bh(v1.w);
  }
  for (; e < end; e += 4) {
    int idx = e + slot;
    if (idx < end) {
      int s = col[idx];
      uint4 v = *(const uint4*)(base + ((size_t)s << 7));
      a0 += bl(v.x); a1 += bh(v.x); a2 += bl(v.y); a3 += bh(v.y);
      a4 += bl(v.z); a5 += bh(v.z); a6 += bl(v.w); a7 += bh(v.w);
    }
  }
#pragma unroll
  for (int st = 16; st <= 32; st <<= 1) {
    a0 += __shfl_xor(a0, st); a1 += __shfl_xor(a1, st);
    a2 += __shfl_xor(a2, st); a3 += __shfl_xor(a3, st);
    a4 += __shfl_xor(a4, st); a5 += __shfl_xor(a5, st);
    a6 += __shfl_xor(a6, st); a7 += __shfl_xor(a7, st);
  }
  if (slot == 0) {
    float w = inv_deg[node];
    int ch = c16 << 3;
    const float* rp = r + ((size_t)node << 7) + ch;
    float4 r0 = *(const float4*)rp;
    float4 r1 = *(const float4*)(rp + 4);
    float4 s0 = *(const float4*)(sc + ch);
    float4 s1 = *(const float4*)(sc + ch + 4);
    float4 h0 = *(const float4*)(sh + ch);
    float4 h1 = *(const float4*)(sh + ch + 4);
    float o0 = fmaxf((a0 * w + r0.x) * s0.x + h0.x, 0.f);
    float o1 = fmaxf((a1 * w + r0.y) * s0.y + h0.y, 0.f);
    float o2 = fmaxf((a2 * w + r0.z) * s0.z + h0.z, 0.f);
    float o3 = fmaxf((a3 * w + r0.w) * s0.w + h0.w, 0.f);
    float o4 = fmaxf((a4 * w + r1.x) * s1.x + h1.x, 0.f);
    float o5 = fmaxf((a5 * w + r1.y) * s1.y + h1.y, 0.f);
    float o6 = fmaxf((a6 * w + r1.z) * s1.z + h1.z, 0.f);
    float o7 = fmaxf((a7 * w + r1.w) * s1.w + h1.w, 0.f);
    unsigned int p0 = (unsigned int)f2b(o0) | ((unsigned int)f2b(o1) << 16);
    unsigned int p1 = (unsigned int)f2b(o2) | ((unsigned int)f2b(o3) << 16);
    unsigned int p2 = (unsigned int)f2b(o4) | ((unsigned int)f2b(o5) << 16);
    unsigned int p3 = (unsigned int)f2b(o6) | ((unsigned int)f2b(o7) << 16);
    *(uint4*)(hbo + ((size_t)node << 7) + ch) = make_uint4(p0, p1, p2, p3);
  }
}

// ---------------- final layer ----------------

__global__ void k_pq(const unsigned short* __restrict__ hb, const float* __restrict__ Wl_out,
                     const float* __restrict__ Wr_out, float* __restrict__ p,
                     float* __restrict__ q, int n) {
  int node = blockIdx.x * 4 + (threadIdx.x >> 6);
  if (node >= n) return;
  int lane = threadIdx.x & 63;
  unsigned int hv = *(const unsigned int*)(hb + ((size_t)node << 7) + (lane << 1));
  float hx = bl(hv), hy = bh(hv);
  float4 wl = *(const float4*)(Wl_out + (lane << 2)); // rows 2l,2l+1; cols 0,1
  float4 wr = *(const float4*)(Wr_out + (lane << 2));
  float p0 = hx * wl.x + hy * wl.z;
  float p1 = hx * wl.y + hy * wl.w;
  float q0 = hx * wr.x + hy * wr.z;
  float q1 = hx * wr.y + hy * wr.w;
#pragma unroll
  for (int off = 32; off > 0; off >>= 1) {
    p0 += __shfl_xor(p0, off, 64);
    p1 += __shfl_xor(p1, off, 64);
    q0 += __shfl_xor(q0, off, 64);
    q1 += __shfl_xor(q1, off, 64);
  }
  if (lane == 0) {
    *(float2*)(p + (size_t)node * 2) = make_float2(p0, p1);
    *(float2*)(q + (size_t)node * 2) = make_float2(q0, q1);
  }
}

__global__ void k_spmm2(const float* __restrict__ p, const float* __restrict__ q,
                        const int* __restrict__ row_ptr, const int* __restrict__ col,
                        const float* __restrict__ inv_deg, const float* __restrict__ b_out,
                        float* __restrict__ out_node, int n) {
  int i = blockIdx.x * blockDim.x + threadIdx.x;
  if (i >= n) return;
  int beg = row_ptr[i], end = row_ptr[i + 1];
  float a0 = 0.f, a1 = 0.f, b0 = 0.f, b1 = 0.f;
  int e = beg;
  for (; e + 2 <= end; e += 2) {
    float2 v0 = *(const float2*)(p + (size_t)col[e] * 2);
    float2 v1 = *(const float2*)(p + (size_t)col[e + 1] * 2);
    a0 += v0.x; a1 += v0.y; b0 += v1.x; b1 += v1.y;
  }
  if (e < end) {
    float2 v = *(const float2*)(p + (size_t)col[e] * 2);
    a0 += v.x; a1 += v.y;
  }
  float w = inv_deg[i];
  float2 qv = *(const float2*)(q + (size_t)i * 2);
  out_node[(size_t)i * 2] = (a0 + b0) * w + qv.x + b_out[0];
  out_node[(size_t)i * 2 + 1] = (a1 + b1) * w + qv.y + b_out[1];
}

__global__ void k_pool(const float* __restrict__ out_node, const int* __restrict__ batch,
                       float* __restrict__ out, float* __restrict__ gcnt, int n) {
  int i = blockIdx.x * blockDim.x + threadIdx.x;
  if (i >= n) return;
  int g = batch[i];
  atomicAdd(&out[g * 2], out_node[(size_t)i * 2]);
  atomicAdd(&out[g * 2 + 1], out_node[(size_t)i * 2 + 1]);
  atomicAdd(&gcnt[g], 1.0f);
}

__global__ void k_div(float* __restrict__ out, const float* __restrict__ gcnt, int ng) {
  int i = blockIdx.x * blockDim.x + threadIdx.x;
  if (i < ng * 2) out[i] /= fmaxf(gcnt[i >> 1], 1.0f);
}

// ---------------- launch ----------------

extern "C" void kernel_launch(void* const* d_in, const int* in_sizes, int n_in,
                              void* d_out, int out_size, void* d_ws, size_t ws_size,
                              hipStream_t stream) {
  const float* x = (const float*)d_in[0];
  const float* Wl = (const float*)d_in[1];
  const float* Wr = (const float*)d_in[2];
  const float* b = (const float*)d_in[3];
  const float* gamma = (const float*)d_in[4];
  const float* beta = (const float*)d_in[5];
  const float* rmean = (const float*)d_in[6];
  const float* rvar = (const float*)d_in[7];
  const float* Wl_out = (const float*)d_in[8];
  const float* Wr_out = (const float*)d_in[9];
  const float* b_out = (const float*)d_in[10];
  const int* eidx = (const int*)d_in[11];
  const int* batch = (const int*)d_in[12];

  const int N = in_sizes[0] / HID;
  const int E = in_sizes[11] / 2;
  const int L = in_sizes[1] / (HID * HID);
  const int NG = out_size / 2;
  const int* src = eidx;
  const int* dst = eidx + E;

  char* ws = (char*)d_ws;
  size_t off = 0;
  auto alloc = [&](size_t bytes) {
    void* ptr = ws + off;
    off += (bytes + 255) & ~(size_t)255;
    return ptr;
  };
  int* row_ptr = (int*)alloc((size_t)(N + 1) * 4);
  int* cursor = (int*)alloc((size_t)N * 4);
  int* col = (int*)alloc((size_t)E * 4);
  float* inv_deg = (float*)alloc((size_t)N * 4);
  unsigned short* xb = (unsigned short*)alloc((size_t)N * HID * 2);
  unsigned short* hb = (unsigned short*)alloc((size_t)N * HID * 2);
  unsigned short* ub = (unsigned short*)alloc((size_t)N * HID * 2);
  float* r = (float*)alloc((size_t)N * HID * 4);
  unsigned short* Wlt = (unsigned short*)alloc((size_t)L * HID * HID * 2);
  unsigned short* Wrt = (unsigned short*)alloc((size_t)L * HID * HID * 2);
  float* sc = (float*)alloc((size_t)L * HID * 4);
  float* sh = (float*)alloc((size_t)L * HID * 4);
  float* p = (float*)alloc((size_t)N * 2 * 4);
  float* q = (float*)alloc((size_t)N * 2 * 4);
  float* gcnt = (float*)alloc((size_t)NG * 4);
  float* out_node = r;  // r is free by the time spmm2 runs

  hipMemsetAsync(cursor, 0, (size_t)N * 4, stream);
  k_count<<<(E / 4 + 255) / 256, 256, 0, stream>>>(dst, cursor, E);
  k_scan<<<1, 1024, 0, stream>>>(cursor, row_ptr, N);
  k_invdeg<<<(N + 255) / 256, 256, 0, stream>>>(row_ptr, inv_deg, N);
  k_fill<<<(E / 4 + 255) / 256, 256, 0, stream>>>(src, dst, cursor, col, E);
  k_x2b<<<(N * HID / 4 + 255) / 256, 256, 0, stream>>>(x, xb, N * HID / 4);
  k_wconv<<<(L * HID * HID + 255) / 256, 256, 0, stream>>>(Wl, Wlt, L * HID * HID);
  k_wconv<<<(L * HID * HID + 255) / 256, 256, 0, stream>>>(Wr, Wrt, L * HID * HID);
  k_bnprep<<<(L * HID + 255) / 256, 256, 0, stream>>>(gamma, beta, rmean, rvar, sc, sh, L * HID);

  const unsigned short* hin = xb;
  for (int l = 0; l < L; ++l) {
    k_gemm<<<(N + 63) / 64, 256, 0, stream>>>(
        hin, Wlt + (size_t)l * HID * HID, Wrt + (size_t)l * HID * HID,
        b + (size_t)l * HID, ub, r, N);
    k_spmm_f<<<(N + 3) / 4, 256, 0, stream>>>(
        ub, r, row_ptr, col, inv_deg, sc + (size_t)l * HID, sh + (size_t)l * HID, hb, N);
    hin = hb;
  }
  k_pq<<<(N + 3) / 4, 256, 0, stream>>>(hin, Wl_out, Wr_out, p, q, N);
  k_spmm2<<<(N + 255) / 256, 256, 0, stream>>>(p, q, row_ptr, col, inv_deg, b_out, out_node, N);
  hipMemsetAsync(d_out, 0, (size_t)out_size * 4, stream);
  hipMemsetAsync(gcnt, 0, (size_t)NG * 4, stream);
  k_pool<<<(N + 255) / 256, 256, 0, stream>>>(out_node, batch, (float*)d_out, gcnt, N);
  k_div<<<(NG * 2 + 255) / 256, 256, 0, stream>>>((float*)d_out, gcnt, NG);
}

// Round 4
// 653.308 us; speedup vs baseline: 2.1634x; 1.3072x over previous
//
#include <hip/hip_runtime.h>

#define HID 128
#define BN_EPS 1e-5f

typedef short bf16x8 __attribute__((ext_vector_type(8)));
typedef float f32x4 __attribute__((ext_vector_type(4)));

__device__ inline unsigned short f2b(float f) {  // f32 -> bf16 RNE
  unsigned int u = __float_as_uint(f);
  unsigned int r = (u + 0x7fffu + ((u >> 16) & 1u)) >> 16;
  return (unsigned short)r;
}
__device__ inline float bl(unsigned int v) { return __uint_as_float(v << 16); }
__device__ inline float bh(unsigned int v) { return __uint_as_float(v & 0xffff0000u); }

// ---------------- bucketed CSR build (bucket = dst >> 8, 256 nodes/bucket) -------
// Random 4B scatters over 6.4MB caused 16x write amplification; bucketing confines
// every scatter to an L2-resident region.

__global__ void k_bhist(const int* __restrict__ dst, int* __restrict__ bcnt, int e, int nb) {
  __shared__ int h[256];
  for (int i = threadIdx.x; i < 256; i += blockDim.x) h[i] = 0;
  __syncthreads();
  int stride = gridDim.x * blockDim.x;
  for (int i = blockIdx.x * blockDim.x + threadIdx.x; i < e; i += stride)
    atomicAdd(&h[dst[i] >> 8], 1);
  __syncthreads();
  for (int i = threadIdx.x; i < nb; i += blockDim.x)
    if (h[i]) atomicAdd(&bcnt[i], h[i]);
}

// single block; nb <= 256
__global__ void k_bscan(const int* __restrict__ bcnt, int* __restrict__ base,
                        int* __restrict__ cur, int nb) {
  __shared__ int ws[4];
  int t = threadIdx.x;
  int v = (t < nb) ? bcnt[t] : 0;
  int lane = t & 63, wid = t >> 6;
  int x = v;
#pragma unroll
  for (int off = 1; off < 64; off <<= 1) {
    int y = __shfl_up(x, off, 64);
    if (lane >= off) x += y;
  }
  if (lane == 63) ws[wid] = x;
  __syncthreads();
  int add = 0;
  for (int w = 0; w < wid; ++w) add += ws[w];
  int incl = x + add;
  int excl = incl - v;
  if (t < nb) { base[t] = excl; cur[t] = excl; }
  if (t == nb - 1) base[nb] = incl;
}

__global__ void k_bscatter(const int* __restrict__ src, const int* __restrict__ dst,
                           int* __restrict__ cur, uint2* __restrict__ binned, int e) {
  __shared__ int bc[256];
  __shared__ int bo[256];
  int nchunk = (e + gridDim.x - 1) / gridDim.x;
  int c0 = blockIdx.x * nchunk;
  int c1 = min(c0 + nchunk, e);
  for (int i = threadIdx.x; i < 256; i += blockDim.x) bc[i] = 0;
  __syncthreads();
  for (int i = c0 + threadIdx.x; i < c1; i += blockDim.x)
    atomicAdd(&bc[dst[i] >> 8], 1);
  __syncthreads();
  for (int i = threadIdx.x; i < 256; i += blockDim.x) {
    int c = bc[i];
    bo[i] = c ? atomicAdd(&cur[i], c) : 0;
    bc[i] = 0;
  }
  __syncthreads();
  for (int i = c0 + threadIdx.x; i < c1; i += blockDim.x) {
    int d = dst[i];
    int b = d >> 8;
    int pos = bo[b] + atomicAdd(&bc[b], 1);
    binned[pos] = make_uint2((unsigned)src[i], (unsigned)d);
  }
}

// one block per bucket: row_ptr, inv_deg, col — all scatters LDS/L2-local
__global__ __launch_bounds__(256) void k_bfill(
    const uint2* __restrict__ binned, const int* __restrict__ base,
    int* __restrict__ row_ptr, float* __restrict__ inv_deg,
    int* __restrict__ col, int n, int nb) {
  __shared__ int cnt[256];
  __shared__ int cur[256];
  __shared__ int ws[4];
  int b = blockIdx.x;
  int t = threadIdx.x;
  int n0 = b << 8;
  int e0 = base[b], e1 = base[b + 1];
  cnt[t] = 0;
  __syncthreads();
  for (int i = e0 + t; i < e1; i += 256)
    atomicAdd(&cnt[binned[i].y & 255], 1);
  __syncthreads();
  int v = cnt[t];
  int lane = t & 63, wid = t >> 6;
  int x = v;
#pragma unroll
  for (int off = 1; off < 64; off <<= 1) {
    int y = __shfl_up(x, off, 64);
    if (lane >= off) x += y;
  }
  if (lane == 63) ws[wid] = x;
  __syncthreads();
  int add = 0;
  for (int w = 0; w < wid; ++w) add += ws[w];
  int excl = x - v + add;
  int node = n0 + t;
  if (node < n) {
    row_ptr[node] = e0 + excl;
    inv_deg[node] = 1.0f / (float)max(v, 1);
  }
  cur[t] = e0 + excl;
  __syncthreads();
  for (int i = e0 + t; i < e1; i += 256) {
    uint2 pr = binned[i];
    int pos = atomicAdd(&cur[pr.y & 255], 1);
    col[pos] = (int)pr.x;
  }
  if (b == 0 && t == 0) row_ptr[n] = base[nb];
}

// ---------------- small prep ----------------

__global__ void k_x2b(const float* __restrict__ x, unsigned short* __restrict__ xb, int n4) {
  int i = blockIdx.x * blockDim.x + threadIdx.x;
  if (i < n4) {
    float4 v = ((const float4*)x)[i];
    unsigned int lo = (unsigned int)f2b(v.x) | ((unsigned int)f2b(v.y) << 16);
    unsigned int hi = (unsigned int)f2b(v.z) | ((unsigned int)f2b(v.w) << 16);
    ((uint2*)xb)[i] = make_uint2(lo, hi);
  }
}

// W [nmats][128][128] (k-major) -> Wt [nmats][128][128] bf16 ([out_ch][k])
__global__ void k_wconv(const float* __restrict__ W, unsigned short* __restrict__ Wt, int total) {
  int i = blockIdx.x * blockDim.x + threadIdx.x;
  if (i < total) {
    int mat = i >> 14, rem = i & 16383, nn = rem >> 7, kk = rem & 127;
    Wt[i] = f2b(W[(mat << 14) + (kk << 7) + nn]);
  }
}

__global__ void k_bnprep(const float* __restrict__ g, const float* __restrict__ be,
                         const float* __restrict__ rm, const float* __restrict__ rv,
                         float* __restrict__ sc, float* __restrict__ sh, int n) {
  int i = blockIdx.x * blockDim.x + threadIdx.x;
  if (i < n) {
    float s = g[i] * rsqrtf(rv[i] + BN_EPS);
    sc[i] = s;
    sh[i] = be[i] - rm[i] * s;
  }
}

// ---------------- MFMA dense: u = h@Wl (bf16), r = h@Wr + b (f32) ----------------
// swapped operands: A = Wt[ch][k], B = hb viewed as [k][node]; D[ch][node].

__global__ __launch_bounds__(256) void k_gemm(
    const unsigned short* __restrict__ hb,   // [n][128] bf16
    const unsigned short* __restrict__ Wlt,  // [128][128] bf16 [out_ch][k]
    const unsigned short* __restrict__ Wrt,
    const float* __restrict__ bias,          // [128]
    unsigned short* __restrict__ u,          // [n][128] bf16
    float* __restrict__ r,                   // [n][128] f32
    int n) {
  int wid = threadIdx.x >> 6;
  int lane = threadIdx.x & 63;
  int l15 = lane & 15, lhi = lane >> 4;
  int node = blockIdx.x * 64 + wid * 16 + l15;
  int nsafe = node < n ? node : 0;
  const unsigned short* hrow = hb + ((size_t)nsafe << 7) + (lhi << 3);
  const unsigned short* wlp = Wlt + (l15 << 7) + (lhi << 3);
  const unsigned short* wrp = Wrt + (l15 << 7) + (lhi << 3);

  f32x4 accU[8], accR[8];
#pragma unroll
  for (int m = 0; m < 8; ++m) { accU[m] = (f32x4)(0.f); accR[m] = (f32x4)(0.f); }

#pragma unroll
  for (int ks = 0; ks < 4; ++ks) {
    bf16x8 bfrag = *(const bf16x8*)(hrow + ks * 32);
#pragma unroll
    for (int m = 0; m < 8; ++m) {
      bf16x8 al = *(const bf16x8*)(wlp + m * 16 * 128 + ks * 32);
      accU[m] = __builtin_amdgcn_mfma_f32_16x16x32_bf16(al, bfrag, accU[m], 0, 0, 0);
      bf16x8 ar = *(const bf16x8*)(wrp + m * 16 * 128 + ks * 32);
      accR[m] = __builtin_amdgcn_mfma_f32_16x16x32_bf16(ar, bfrag, accR[m], 0, 0, 0);
    }
  }

  if (node < n) {
#pragma unroll
    for (int m = 0; m < 8; ++m) {
      int ch = m * 16 + (lhi << 2);  // 4 consecutive channels
      unsigned int lo = (unsigned int)f2b(accU[m][0]) | ((unsigned int)f2b(accU[m][1]) << 16);
      unsigned int hi = (unsigned int)f2b(accU[m][2]) | ((unsigned int)f2b(accU[m][3]) << 16);
      *(uint2*)(u + ((size_t)node << 7) + ch) = make_uint2(lo, hi);
      float4 bi = *(const float4*)(bias + ch);
      *(float4*)(r + ((size_t)node << 7) + ch) =
          make_float4(accR[m][0] + bi.x, accR[m][1] + bi.y, accR[m][2] + bi.z, accR[m][3] + bi.w);
    }
  }
}

// ---------------- fused SpMM: hb_out = relu(bn(mean-gather(u) + r)) ----------------
// wave per node: 4 edge-slots x 16 channel-lanes (8 ch each, 16B gathers), 16-edge unroll

__global__ __launch_bounds__(256) void k_spmm_f(
    const unsigned short* __restrict__ u, const float* __restrict__ r,
    const int* __restrict__ row_ptr, const int* __restrict__ col,
    const float* __restrict__ inv_deg, const float* __restrict__ sc,
    const float* __restrict__ sh, unsigned short* __restrict__ hbo, int n) {
  int node = blockIdx.x * 4 + (threadIdx.x >> 6);
  if (node >= n) return;
  int lane = threadIdx.x & 63;
  int slot = lane >> 4, c16 = lane & 15;
  int beg = row_ptr[node], end = row_ptr[node + 1];
  float a0 = 0, a1 = 0, a2 = 0, a3 = 0, a4 = 0, a5 = 0, a6 = 0, a7 = 0;
  const unsigned short* base = u + (c16 << 3);
  int e = beg;
  for (; e + 16 <= end; e += 16) {
    int s0 = col[e + slot];
    int s1 = col[e + 4 + slot];
    int s2 = col[e + 8 + slot];
    int s3 = col[e + 12 + slot];
    uint4 v0 = *(const uint4*)(base + ((size_t)s0 << 7));
    uint4 v1 = *(const uint4*)(base + ((size_t)s1 << 7));
    uint4 v2 = *(const uint4*)(base + ((size_t)s2 << 7));
    uint4 v3 = *(const uint4*)(base + ((size_t)s3 << 7));
    a0 += bl(v0.x); a1 += bh(v0.x); a2 += bl(v0.y); a3 += bh(v0.y);
    a4 += bl(v0.z); a5 += bh(v0.z); a6 += bl(v0.w); a7 += bh(v0.w);
    a0 += bl(v1.x); a1 += bh(v1.x); a2 += bl(v1.y); a3 += bh(v1.y);
    a4 += bl(v1.z); a5 += bh(v1.z); a6 += bl(v1.w); a7 += bh(v1.w);
    a0 += bl(v2.x); a1 += bh(v2.x); a2 += bl(v2.y); a3 += bh(v2.y);
    a4 += bl(v2.z); a5 += bh(v2.z); a6 += bl(v2.w); a7 += bh(v2.w);
    a0 += bl(v3.x); a1 += bh(v3.x); a2 += bl(v3.y); a3 += bh(v3.y);
    a4 += bl(v3.z); a5 += bh(v3.z); a6 += bl(v3.w); a7 += bh(v3.w);
  }
  for (; e < end; e += 4) {
    int idx = e + slot;
    if (idx < end) {
      int s = col[idx];
      uint4 v = *(const uint4*)(base + ((size_t)s << 7));
      a0 += bl(v.x); a1 += bh(v.x); a2 += bl(v.y); a3 += bh(v.y);
      a4 += bl(v.z); a5 += bh(v.z); a6 += bl(v.w); a7 += bh(v.w);
    }
  }
#pragma unroll
  for (int st = 16; st <= 32; st <<= 1) {
    a0 += __shfl_xor(a0, st); a1 += __shfl_xor(a1, st);
    a2 += __shfl_xor(a2, st); a3 += __shfl_xor(a3, st);
    a4 += __shfl_xor(a4, st); a5 += __shfl_xor(a5, st);
    a6 += __shfl_xor(a6, st); a7 += __shfl_xor(a7, st);
  }
  if (slot == 0) {
    float w = inv_deg[node];
    int ch = c16 << 3;
    const float* rp = r + ((size_t)node << 7) + ch;
    float4 r0 = *(const float4*)rp;
    float4 r1 = *(const float4*)(rp + 4);
    float4 s0 = *(const float4*)(sc + ch);
    float4 s1 = *(const float4*)(sc + ch + 4);
    float4 h0 = *(const float4*)(sh + ch);
    float4 h1 = *(const float4*)(sh + ch + 4);
    float o0 = fmaxf((a0 * w + r0.x) * s0.x + h0.x, 0.f);
    float o1 = fmaxf((a1 * w + r0.y) * s0.y + h0.y, 0.f);
    float o2 = fmaxf((a2 * w + r0.z) * s0.z + h0.z, 0.f);
    float o3 = fmaxf((a3 * w + r0.w) * s0.w + h0.w, 0.f);
    float o4 = fmaxf((a4 * w + r1.x) * s1.x + h1.x, 0.f);
    float o5 = fmaxf((a5 * w + r1.y) * s1.y + h1.y, 0.f);
    float o6 = fmaxf((a6 * w + r1.z) * s1.z + h1.z, 0.f);
    float o7 = fmaxf((a7 * w + r1.w) * s1.w + h1.w, 0.f);
    unsigned int p0 = (unsigned int)f2b(o0) | ((unsigned int)f2b(o1) << 16);
    unsigned int p1 = (unsigned int)f2b(o2) | ((unsigned int)f2b(o3) << 16);
    unsigned int p2 = (unsigned int)f2b(o4) | ((unsigned int)f2b(o5) << 16);
    unsigned int p3 = (unsigned int)f2b(o6) | ((unsigned int)f2b(o7) << 16);
    *(uint4*)(hbo + ((size_t)node << 7) + ch) = make_uint4(p0, p1, p2, p3);
  }
}

// ---------------- final layer ----------------

__global__ void k_pq(const unsigned short* __restrict__ hb, const float* __restrict__ Wl_out,
                     const float* __restrict__ Wr_out, float* __restrict__ p,
                     float* __restrict__ q, int n) {
  int node = blockIdx.x * 4 + (threadIdx.x >> 6);
  if (node >= n) return;
  int lane = threadIdx.x & 63;
  unsigned int hv = *(const unsigned int*)(hb + ((size_t)node << 7) + (lane << 1));
  float hx = bl(hv), hy = bh(hv);
  float4 wl = *(const float4*)(Wl_out + (lane << 2)); // rows 2l,2l+1; cols 0,1
  float4 wr = *(const float4*)(Wr_out + (lane << 2));
  float p0 = hx * wl.x + hy * wl.z;
  float p1 = hx * wl.y + hy * wl.w;
  float q0 = hx * wr.x + hy * wr.z;
  float q1 = hx * wr.y + hy * wr.w;
#pragma unroll
  for (int off = 32; off > 0; off >>= 1) {
    p0 += __shfl_xor(p0, off, 64);
    p1 += __shfl_xor(p1, off, 64);
    q0 += __shfl_xor(q0, off, 64);
    q1 += __shfl_xor(q1, off, 64);
  }
  if (lane == 0) {
    *(float2*)(p + (size_t)node * 2) = make_float2(p0, p1);
    *(float2*)(q + (size_t)node * 2) = make_float2(q0, q1);
  }
}

__global__ void k_spmm2(const float* __restrict__ p, const float* __restrict__ q,
                        const int* __restrict__ row_ptr, const int* __restrict__ col,
                        const float* __restrict__ inv_deg, const float* __restrict__ b_out,
                        float* __restrict__ out_node, int n) {
  int i = blockIdx.x * blockDim.x + threadIdx.x;
  if (i >= n) return;
  int beg = row_ptr[i], end = row_ptr[i + 1];
  float a0 = 0.f, a1 = 0.f, b0 = 0.f, b1 = 0.f;
  int e = beg;
  for (; e + 2 <= end; e += 2) {
    float2 v0 = *(const float2*)(p + (size_t)col[e] * 2);
    float2 v1 = *(const float2*)(p + (size_t)col[e + 1] * 2);
    a0 += v0.x; a1 += v0.y; b0 += v1.x; b1 += v1.y;
  }
  if (e < end) {
    float2 v = *(const float2*)(p + (size_t)col[e] * 2);
    a0 += v.x; a1 += v.y;
  }
  float w = inv_deg[i];
  float2 qv = *(const float2*)(q + (size_t)i * 2);
  out_node[(size_t)i * 2] = (a0 + b0) * w + qv.x + b_out[0];
  out_node[(size_t)i * 2 + 1] = (a1 + b1) * w + qv.y + b_out[1];
}

__global__ void k_pool(const float* __restrict__ out_node, const int* __restrict__ batch,
                       float* __restrict__ out, float* __restrict__ gcnt, int n) {
  int i = blockIdx.x * blockDim.x + threadIdx.x;
  if (i >= n) return;
  int g = batch[i];
  atomicAdd(&out[g * 2], out_node[(size_t)i * 2]);
  atomicAdd(&out[g * 2 + 1], out_node[(size_t)i * 2 + 1]);
  atomicAdd(&gcnt[g], 1.0f);
}

__global__ void k_div(float* __restrict__ out, const float* __restrict__ gcnt, int ng) {
  int i = blockIdx.x * blockDim.x + threadIdx.x;
  if (i < ng * 2) out[i] /= fmaxf(gcnt[i >> 1], 1.0f);
}

// ---------------- launch ----------------

extern "C" void kernel_launch(void* const* d_in, const int* in_sizes, int n_in,
                              void* d_out, int out_size, void* d_ws, size_t ws_size,
                              hipStream_t stream) {
  const float* x = (const float*)d_in[0];
  const float* Wl = (const float*)d_in[1];
  const float* Wr = (const float*)d_in[2];
  const float* b = (const float*)d_in[3];
  const float* gamma = (const float*)d_in[4];
  const float* beta = (const float*)d_in[5];
  const float* rmean = (const float*)d_in[6];
  const float* rvar = (const float*)d_in[7];
  const float* Wl_out = (const float*)d_in[8];
  const float* Wr_out = (const float*)d_in[9];
  const float* b_out = (const float*)d_in[10];
  const int* eidx = (const int*)d_in[11];
  const int* batch = (const int*)d_in[12];

  const int N = in_sizes[0] / HID;
  const int E = in_sizes[11] / 2;
  const int L = in_sizes[1] / (HID * HID);
  const int NG = out_size / 2;
  const int NB = (N + 255) >> 8;  // nodes/bucket = 256; requires N <= 65536
  const int* src = eidx;
  const int* dst = eidx + E;

  char* ws = (char*)d_ws;
  size_t off = 0;
  auto alloc = [&](size_t bytes) {
    void* ptr = ws + off;
    off += (bytes + 255) & ~(size_t)255;
    return ptr;
  };
  int* row_ptr = (int*)alloc((size_t)(N + 1) * 4);
  int* bcnt = (int*)alloc((size_t)NB * 4);
  int* bbase = (int*)alloc((size_t)(NB + 1) * 4);
  int* bcur = (int*)alloc((size_t)NB * 4);
  int* col = (int*)alloc((size_t)E * 4);
  float* inv_deg = (float*)alloc((size_t)N * 4);
  unsigned short* xb = (unsigned short*)alloc((size_t)N * HID * 2);
  unsigned short* hb = (unsigned short*)alloc((size_t)N * HID * 2);
  unsigned short* ub = (unsigned short*)alloc((size_t)N * HID * 2);
  float* r = (float*)alloc((size_t)N * HID * 4);
  unsigned short* Wlt = (unsigned short*)alloc((size_t)L * HID * HID * 2);
  unsigned short* Wrt = (unsigned short*)alloc((size_t)L * HID * HID * 2);
  float* sc = (float*)alloc((size_t)L * HID * 4);
  float* sh = (float*)alloc((size_t)L * HID * 4);
  float* p = (float*)alloc((size_t)N * 2 * 4);
  float* q = (float*)alloc((size_t)N * 2 * 4);
  float* gcnt = (float*)alloc((size_t)NG * 4);
  uint2* binned = (uint2*)r;      // binned (8B*E) dead before r is first written
  float* out_node = r;            // r free by the time spmm2 runs

  hipMemsetAsync(bcnt, 0, (size_t)NB * 4, stream);
  k_bhist<<<256, 256, 0, stream>>>(dst, bcnt, E, NB);
  k_bscan<<<1, 256, 0, stream>>>(bcnt, bbase, bcur, NB);
  k_bscatter<<<256, 256, 0, stream>>>(src, dst, bcur, binned, E);
  k_bfill<<<NB, 256, 0, stream>>>(binned, bbase, row_ptr, inv_deg, col, N, NB);

  k_x2b<<<(N * HID / 4 + 255) / 256, 256, 0, stream>>>(x, xb, N * HID / 4);
  k_wconv<<<(L * HID * HID + 255) / 256, 256, 0, stream>>>(Wl, Wlt, L * HID * HID);
  k_wconv<<<(L * HID * HID + 255) / 256, 256, 0, stream>>>(Wr, Wrt, L * HID * HID);
  k_bnprep<<<(L * HID + 255) / 256, 256, 0, stream>>>(gamma, beta, rmean, rvar, sc, sh, L * HID);

  const unsigned short* hin = xb;
  for (int l = 0; l < L; ++l) {
    k_gemm<<<(N + 63) / 64, 256, 0, stream>>>(
        hin, Wlt + (size_t)l * HID * HID, Wrt + (size_t)l * HID * HID,
        b + (size_t)l * HID, ub, r, N);
    k_spmm_f<<<(N + 3) / 4, 256, 0, stream>>>(
        ub, r, row_ptr, col, inv_deg, sc + (size_t)l * HID, sh + (size_t)l * HID, hb, N);
    hin = hb;
  }
  k_pq<<<(N + 3) / 4, 256, 0, stream>>>(hin, Wl_out, Wr_out, p, q, N);
  k_spmm2<<<(N + 255) / 256, 256, 0, stream>>>(p, q, row_ptr, col, inv_deg, b_out, out_node, N);
  hipMemsetAsync(d_out, 0, (size_t)out_size * 4, stream);
  hipMemsetAsync(gcnt, 0, (size_t)NG * 4, stream);
  k_pool<<<(N + 255) / 256, 256, 0, stream>>>(out_node, batch, (float*)d_out, gcnt, N);
  k_div<<<(NG * 2 + 255) / 256, 256, 0, stream>>>((float*)d_out, gcnt, NG);
}

// Round 5
// 602.032 us; speedup vs baseline: 2.3477x; 1.0852x over previous
//
#include <hip/hip_runtime.h>

#define HID 128
#define BN_EPS 1e-5f

typedef short bf16x8 __attribute__((ext_vector_type(8)));
typedef float f32x4 __attribute__((ext_vector_type(4)));

__device__ inline unsigned short f2b(float f) {  // f32 -> bf16 RNE
  unsigned int u = __float_as_uint(f);
  unsigned int r = (u + 0x7fffu + ((u >> 16) & 1u)) >> 16;
  return (unsigned short)r;
}
__device__ inline float bl(unsigned int v) { return __uint_as_float(v << 16); }
__device__ inline float bh(unsigned int v) { return __uint_as_float(v & 0xffff0000u); }

// ---------------- bucketed CSR build (bucket = dst >> 8, 256 nodes/bucket) -------

__global__ void k_bhist(const int* __restrict__ dst, int* __restrict__ bcnt, int e, int nb) {
  __shared__ int h[256];
  for (int i = threadIdx.x; i < 256; i += blockDim.x) h[i] = 0;
  __syncthreads();
  int stride = gridDim.x * blockDim.x;
  for (int i = blockIdx.x * blockDim.x + threadIdx.x; i < e; i += stride)
    atomicAdd(&h[dst[i] >> 8], 1);
  __syncthreads();
  for (int i = threadIdx.x; i < nb; i += blockDim.x)
    if (h[i]) atomicAdd(&bcnt[i], h[i]);
}

// single block; nb <= 256
__global__ void k_bscan(const int* __restrict__ bcnt, int* __restrict__ base,
                        int* __restrict__ cur, int nb) {
  __shared__ int ws[4];
  int t = threadIdx.x;
  int v = (t < nb) ? bcnt[t] : 0;
  int lane = t & 63, wid = t >> 6;
  int x = v;
#pragma unroll
  for (int off = 1; off < 64; off <<= 1) {
    int y = __shfl_up(x, off, 64);
    if (lane >= off) x += y;
  }
  if (lane == 63) ws[wid] = x;
  __syncthreads();
  int add = 0;
  for (int w = 0; w < wid; ++w) add += ws[w];
  int incl = x + add;
  int excl = incl - v;
  if (t < nb) { base[t] = excl; cur[t] = excl; }
  if (t == nb - 1) base[nb] = incl;
}

__global__ void k_bscatter(const int* __restrict__ src, const int* __restrict__ dst,
                           int* __restrict__ cur, uint2* __restrict__ binned, int e) {
  __shared__ int bc[256];
  __shared__ int bo[256];
  int nchunk = (e + gridDim.x - 1) / gridDim.x;
  int c0 = blockIdx.x * nchunk;
  int c1 = min(c0 + nchunk, e);
  for (int i = threadIdx.x; i < 256; i += blockDim.x) bc[i] = 0;
  __syncthreads();
  for (int i = c0 + threadIdx.x; i < c1; i += blockDim.x)
    atomicAdd(&bc[dst[i] >> 8], 1);
  __syncthreads();
  for (int i = threadIdx.x; i < 256; i += blockDim.x) {
    int c = bc[i];
    bo[i] = c ? atomicAdd(&cur[i], c) : 0;
    bc[i] = 0;
  }
  __syncthreads();
  for (int i = c0 + threadIdx.x; i < c1; i += blockDim.x) {
    int d = dst[i];
    int b = d >> 8;
    int pos = bo[b] + atomicAdd(&bc[b], 1);
    binned[pos] = make_uint2((unsigned)src[i], (unsigned)d);
  }
}

// one block per bucket: row_ptr, inv_deg, col — all scatters LDS/L2-local
__global__ __launch_bounds__(256) void k_bfill(
    const uint2* __restrict__ binned, const int* __restrict__ base,
    int* __restrict__ row_ptr, float* __restrict__ inv_deg,
    int* __restrict__ col, int n, int nb) {
  __shared__ int cnt[256];
  __shared__ int cur[256];
  __shared__ int ws[4];
  int b = blockIdx.x;
  int t = threadIdx.x;
  int n0 = b << 8;
  int e0 = base[b], e1 = base[b + 1];
  cnt[t] = 0;
  __syncthreads();
  for (int i = e0 + t; i < e1; i += 256)
    atomicAdd(&cnt[binned[i].y & 255], 1);
  __syncthreads();
  int v = cnt[t];
  int lane = t & 63, wid = t >> 6;
  int x = v;
#pragma unroll
  for (int off = 1; off < 64; off <<= 1) {
    int y = __shfl_up(x, off, 64);
    if (lane >= off) x += y;
  }
  if (lane == 63) ws[wid] = x;
  __syncthreads();
  int add = 0;
  for (int w = 0; w < wid; ++w) add += ws[w];
  int excl = x - v + add;
  int node = n0 + t;
  if (node < n) {
    row_ptr[node] = e0 + excl;
    inv_deg[node] = 1.0f / (float)max(v, 1);
  }
  cur[t] = e0 + excl;
  __syncthreads();
  for (int i = e0 + t; i < e1; i += 256) {
    uint2 pr = binned[i];
    int pos = atomicAdd(&cur[pr.y & 255], 1);
    col[pos] = (int)pr.x;
  }
  if (b == 0 && t == 0) row_ptr[n] = base[nb];
}

// ---------------- small prep ----------------

__global__ void k_x2b(const float* __restrict__ x, unsigned short* __restrict__ xb, int n4) {
  int i = blockIdx.x * blockDim.x + threadIdx.x;
  if (i < n4) {
    float4 v = ((const float4*)x)[i];
    unsigned int lo = (unsigned int)f2b(v.x) | ((unsigned int)f2b(v.y) << 16);
    unsigned int hi = (unsigned int)f2b(v.z) | ((unsigned int)f2b(v.w) << 16);
    ((uint2*)xb)[i] = make_uint2(lo, hi);
  }
}

// W [nmats][128][128] (k-major) -> Wt [nmats][128][128] bf16 ([out_ch][k])
__global__ void k_wconv(const float* __restrict__ W, unsigned short* __restrict__ Wt, int total) {
  int i = blockIdx.x * blockDim.x + threadIdx.x;
  if (i < total) {
    int mat = i >> 14, rem = i & 16383, nn = rem >> 7, kk = rem & 127;
    Wt[i] = f2b(W[(mat << 14) + (kk << 7) + nn]);
  }
}

__global__ void k_bnprep(const float* __restrict__ g, const float* __restrict__ be,
                         const float* __restrict__ rm, const float* __restrict__ rv,
                         float* __restrict__ sc, float* __restrict__ sh, int n) {
  int i = blockIdx.x * blockDim.x + threadIdx.x;
  if (i < n) {
    float s = g[i] * rsqrtf(rv[i] + BN_EPS);
    sc[i] = s;
    sh[i] = be[i] - rm[i] * s;
  }
}

// ---------------- MFMA dense: u = h@Wl (bf16), r = h@Wr + b (f32) ----------------

__global__ __launch_bounds__(256) void k_gemm(
    const unsigned short* __restrict__ hb,   // [n][128] bf16
    const unsigned short* __restrict__ Wlt,  // [128][128] bf16 [out_ch][k]
    const unsigned short* __restrict__ Wrt,
    const float* __restrict__ bias,          // [128]
    unsigned short* __restrict__ u,          // [n][128] bf16
    float* __restrict__ r,                   // [n][128] f32
    int n) {
  int wid = threadIdx.x >> 6;
  int lane = threadIdx.x & 63;
  int l15 = lane & 15, lhi = lane >> 4;
  int node = blockIdx.x * 64 + wid * 16 + l15;
  int nsafe = node < n ? node : 0;
  const unsigned short* hrow = hb + ((size_t)nsafe << 7) + (lhi << 3);
  const unsigned short* wlp = Wlt + (l15 << 7) + (lhi << 3);
  const unsigned short* wrp = Wrt + (l15 << 7) + (lhi << 3);

  f32x4 accU[8], accR[8];
#pragma unroll
  for (int m = 0; m < 8; ++m) { accU[m] = (f32x4)(0.f); accR[m] = (f32x4)(0.f); }

#pragma unroll
  for (int ks = 0; ks < 4; ++ks) {
    bf16x8 bfrag = *(const bf16x8*)(hrow + ks * 32);
#pragma unroll
    for (int m = 0; m < 8; ++m) {
      bf16x8 al = *(const bf16x8*)(wlp + m * 16 * 128 + ks * 32);
      accU[m] = __builtin_amdgcn_mfma_f32_16x16x32_bf16(al, bfrag, accU[m], 0, 0, 0);
      bf16x8 ar = *(const bf16x8*)(wrp + m * 16 * 128 + ks * 32);
      accR[m] = __builtin_amdgcn_mfma_f32_16x16x32_bf16(ar, bfrag, accR[m], 0, 0, 0);
    }
  }

  if (node < n) {
#pragma unroll
    for (int m = 0; m < 8; ++m) {
      int ch = m * 16 + (lhi << 2);  // 4 consecutive channels
      unsigned int lo = (unsigned int)f2b(accU[m][0]) | ((unsigned int)f2b(accU[m][1]) << 16);
      unsigned int hi = (unsigned int)f2b(accU[m][2]) | ((unsigned int)f2b(accU[m][3]) << 16);
      *(uint2*)(u + ((size_t)node << 7) + ch) = make_uint2(lo, hi);
      float4 bi = *(const float4*)(bias + ch);
      *(float4*)(r + ((size_t)node << 7) + ch) =
          make_float4(accR[m][0] + bi.x, accR[m][1] + bi.y, accR[m][2] + bi.z, accR[m][3] + bi.w);
    }
  }
}

// ---------------- fused SpMM: hb_out = relu(bn(mean-gather(u) + r)) ----------------

__global__ __launch_bounds__(256) void k_spmm_f(
    const unsigned short* __restrict__ u, const float* __restrict__ r,
    const int* __restrict__ row_ptr, const int* __restrict__ col,
    const float* __restrict__ inv_deg, const float* __restrict__ sc,
    const float* __restrict__ sh, unsigned short* __restrict__ hbo, int n) {
  int node = blockIdx.x * 4 + (threadIdx.x >> 6);
  if (node >= n) return;
  int lane = threadIdx.x & 63;
  int slot = lane >> 4, c16 = lane & 15;
  int beg = row_ptr[node], end = row_ptr[node + 1];
  float a0 = 0, a1 = 0, a2 = 0, a3 = 0, a4 = 0, a5 = 0, a6 = 0, a7 = 0;
  const unsigned short* base = u + (c16 << 3);
  int e = beg;
  for (; e + 16 <= end; e += 16) {
    int s0 = col[e + slot];
    int s1 = col[e + 4 + slot];
    int s2 = col[e + 8 + slot];
    int s3 = col[e + 12 + slot];
    uint4 v0 = *(const uint4*)(base + ((size_t)s0 << 7));
    uint4 v1 = *(const uint4*)(base + ((size_t)s1 << 7));
    uint4 v2 = *(const uint4*)(base + ((size_t)s2 << 7));
    uint4 v3 = *(const uint4*)(base + ((size_t)s3 << 7));
    a0 += bl(v0.x); a1 += bh(v0.x); a2 += bl(v0.y); a3 += bh(v0.y);
    a4 += bl(v0.z); a5 += bh(v0.z); a6 += bl(v0.w); a7 += bh(v0.w);
    a0 += bl(v1.x); a1 += bh(v1.x); a2 += bl(v1.y); a3 += bh(v1.y);
    a4 += bl(v1.z); a5 += bh(v1.z); a6 += bl(v1.w); a7 += bh(v1.w);
    a0 += bl(v2.x); a1 += bh(v2.x); a2 += bl(v2.y); a3 += bh(v2.y);
    a4 += bl(v2.z); a5 += bh(v2.z); a6 += bl(v2.w); a7 += bh(v2.w);
    a0 += bl(v3.x); a1 += bh(v3.x); a2 += bl(v3.y); a3 += bh(v3.y);
    a4 += bl(v3.z); a5 += bh(v3.z); a6 += bl(v3.w); a7 += bh(v3.w);
  }
  for (; e < end; e += 4) {
    int idx = e + slot;
    if (idx < end) {
      int s = col[idx];
      uint4 v = *(const uint4*)(base + ((size_t)s << 7));
      a0 += bl(v.x); a1 += bh(v.x); a2 += bl(v.y); a3 += bh(v.y);
      a4 += bl(v.z); a5 += bh(v.z); a6 += bl(v.w); a7 += bh(v.w);
    }
  }
#pragma unroll
  for (int st = 16; st <= 32; st <<= 1) {
    a0 += __shfl_xor(a0, st); a1 += __shfl_xor(a1, st);
    a2 += __shfl_xor(a2, st); a3 += __shfl_xor(a3, st);
    a4 += __shfl_xor(a4, st); a5 += __shfl_xor(a5, st);
    a6 += __shfl_xor(a6, st); a7 += __shfl_xor(a7, st);
  }
  if (slot == 0) {
    float w = inv_deg[node];
    int ch = c16 << 3;
    const float* rp = r + ((size_t)node << 7) + ch;
    float4 r0 = *(const float4*)rp;
    float4 r1 = *(const float4*)(rp + 4);
    float4 s0 = *(const float4*)(sc + ch);
    float4 s1 = *(const float4*)(sc + ch + 4);
    float4 h0 = *(const float4*)(sh + ch);
    float4 h1 = *(const float4*)(sh + ch + 4);
    float o0 = fmaxf((a0 * w + r0.x) * s0.x + h0.x, 0.f);
    float o1 = fmaxf((a1 * w + r0.y) * s0.y + h0.y, 0.f);
    float o2 = fmaxf((a2 * w + r0.z) * s0.z + h0.z, 0.f);
    float o3 = fmaxf((a3 * w + r0.w) * s0.w + h0.w, 0.f);
    float o4 = fmaxf((a4 * w + r1.x) * s1.x + h1.x, 0.f);
    float o5 = fmaxf((a5 * w + r1.y) * s1.y + h1.y, 0.f);
    float o6 = fmaxf((a6 * w + r1.z) * s1.z + h1.z, 0.f);
    float o7 = fmaxf((a7 * w + r1.w) * s1.w + h1.w, 0.f);
    unsigned int p0 = (unsigned int)f2b(o0) | ((unsigned int)f2b(o1) << 16);
    unsigned int p1 = (unsigned int)f2b(o2) | ((unsigned int)f2b(o3) << 16);
    unsigned int p2 = (unsigned int)f2b(o4) | ((unsigned int)f2b(o5) << 16);
    unsigned int p3 = (unsigned int)f2b(o6) | ((unsigned int)f2b(o7) << 16);
    *(uint4*)(hbo + ((size_t)node << 7) + ch) = make_uint4(p0, p1, p2, p3);
  }
}

// ---------------- final layer ----------------

__global__ void k_pq(const unsigned short* __restrict__ hb, const float* __restrict__ Wl_out,
                     const float* __restrict__ Wr_out, float* __restrict__ p,
                     float* __restrict__ q, int n) {
  int node = blockIdx.x * 4 + (threadIdx.x >> 6);
  if (node >= n) return;
  int lane = threadIdx.x & 63;
  unsigned int hv = *(const unsigned int*)(hb + ((size_t)node << 7) + (lane << 1));
  float hx = bl(hv), hy = bh(hv);
  float4 wl = *(const float4*)(Wl_out + (lane << 2)); // rows 2l,2l+1; cols 0,1
  float4 wr = *(const float4*)(Wr_out + (lane << 2));
  float p0 = hx * wl.x + hy * wl.z;
  float p1 = hx * wl.y + hy * wl.w;
  float q0 = hx * wr.x + hy * wr.z;
  float q1 = hx * wr.y + hy * wr.w;
#pragma unroll
  for (int off = 32; off > 0; off >>= 1) {
    p0 += __shfl_xor(p0, off, 64);
    p1 += __shfl_xor(p1, off, 64);
    q0 += __shfl_xor(q0, off, 64);
    q1 += __shfl_xor(q1, off, 64);
  }
  if (lane == 0) {
    *(float2*)(p + (size_t)node * 2) = make_float2(p0, p1);
    *(float2*)(q + (size_t)node * 2) = make_float2(q0, q1);
  }
}

__global__ void k_spmm2(const float* __restrict__ p, const float* __restrict__ q,
                        const int* __restrict__ row_ptr, const int* __restrict__ col,
                        const float* __restrict__ inv_deg, const float* __restrict__ b_out,
                        float* __restrict__ out_node, int n) {
  int i = blockIdx.x * blockDim.x + threadIdx.x;
  if (i >= n) return;
  int beg = row_ptr[i], end = row_ptr[i + 1];
  float a0 = 0.f, a1 = 0.f, b0 = 0.f, b1 = 0.f;
  int e = beg;
  for (; e + 2 <= end; e += 2) {
    float2 v0 = *(const float2*)(p + (size_t)col[e] * 2);
    float2 v1 = *(const float2*)(p + (size_t)col[e + 1] * 2);
    a0 += v0.x; a1 += v0.y; b0 += v1.x; b1 += v1.y;
  }
  if (e < end) {
    float2 v = *(const float2*)(p + (size_t)col[e] * 2);
    a0 += v.x; a1 += v.y;
  }
  float w = inv_deg[i];
  float2 qv = *(const float2*)(q + (size_t)i * 2);
  out_node[(size_t)i * 2] = (a0 + b0) * w + qv.x + b_out[0];
  out_node[(size_t)i * 2 + 1] = (a1 + b1) * w + qv.y + b_out[1];
}

// ---- pool: batch is SORTED -> wave-level segmented reduction, ~1 atomic per run ----

__global__ void k_pool(const float* __restrict__ out_node, const int* __restrict__ batch,
                       float* __restrict__ out, float* __restrict__ gcnt, int n) {
  int i = blockIdx.x * blockDim.x + threadIdx.x;
  int lane = threadIdx.x & 63;
  bool valid = i < n;
  int g = valid ? batch[i] : -1;
  float v0 = valid ? out_node[(size_t)i * 2] : 0.f;
  float v1 = valid ? out_node[(size_t)i * 2 + 1] : 0.f;
  float s0 = v0, s1 = v1;
#pragma unroll
  for (int off = 1; off < 64; off <<= 1) {
    float y0 = __shfl_up(s0, off, 64);
    float y1 = __shfl_up(s1, off, 64);
    if (lane >= off) { s0 += y0; s1 += y1; }
  }
  int gprev = __shfl_up(g, 1, 64);
  int gnext = __shfl_down(g, 1, 64);
  bool is_start = (lane == 0) || (g != gprev);
  bool is_end = valid && ((lane == 63) || (g != gnext));
  int startl = is_start ? lane : 0;
#pragma unroll
  for (int off = 1; off < 64; off <<= 1) {
    int y = __shfl_up(startl, off, 64);
    if (lane >= off) startl = max(startl, y);
  }
  int prevl = startl > 0 ? startl - 1 : 0;
  float t0 = __shfl(s0, prevl, 64);
  float t1 = __shfl(s1, prevl, 64);
  if (is_end) {
    float p0 = startl > 0 ? t0 : 0.f;
    float p1 = startl > 0 ? t1 : 0.f;
    atomicAdd(&out[g * 2], s0 - p0);
    atomicAdd(&out[g * 2 + 1], s1 - p1);
    atomicAdd(&gcnt[g], (float)(lane - startl + 1));
  }
}

__global__ void k_div(float* __restrict__ out, const float* __restrict__ gcnt, int ng) {
  int i = blockIdx.x * blockDim.x + threadIdx.x;
  if (i < ng * 2) out[i] /= fmaxf(gcnt[i >> 1], 1.0f);
}

// ---------------- launch ----------------

extern "C" void kernel_launch(void* const* d_in, const int* in_sizes, int n_in,
                              void* d_out, int out_size, void* d_ws, size_t ws_size,
                              hipStream_t stream) {
  const float* x = (const float*)d_in[0];
  const float* Wl = (const float*)d_in[1];
  const float* Wr = (const float*)d_in[2];
  const float* b = (const float*)d_in[3];
  const float* gamma = (const float*)d_in[4];
  const float* beta = (const float*)d_in[5];
  const float* rmean = (const float*)d_in[6];
  const float* rvar = (const float*)d_in[7];
  const float* Wl_out = (const float*)d_in[8];
  const float* Wr_out = (const float*)d_in[9];
  const float* b_out = (const float*)d_in[10];
  const int* eidx = (const int*)d_in[11];
  const int* batch = (const int*)d_in[12];

  const int N = in_sizes[0] / HID;
  const int E = in_sizes[11] / 2;
  const int L = in_sizes[1] / (HID * HID);
  const int NG = out_size / 2;
  const int NB = (N + 255) >> 8;  // nodes/bucket = 256; requires N <= 65536
  const int* src = eidx;
  const int* dst = eidx + E;

  char* ws = (char*)d_ws;
  size_t off = 0;
  auto alloc = [&](size_t bytes) {
    void* ptr = ws + off;
    off += (bytes + 255) & ~(size_t)255;
    return ptr;
  };
  int* row_ptr = (int*)alloc((size_t)(N + 1) * 4);
  int* bcnt = (int*)alloc((size_t)NB * 4);
  int* bbase = (int*)alloc((size_t)(NB + 1) * 4);
  int* bcur = (int*)alloc((size_t)NB * 4);
  int* col = (int*)alloc((size_t)E * 4);
  float* inv_deg = (float*)alloc((size_t)N * 4);
  unsigned short* xb = (unsigned short*)alloc((size_t)N * HID * 2);
  unsigned short* hb = (unsigned short*)alloc((size_t)N * HID * 2);
  unsigned short* ub = (unsigned short*)alloc((size_t)N * HID * 2);
  float* r = (float*)alloc((size_t)N * HID * 4);
  unsigned short* Wlt = (unsigned short*)alloc((size_t)L * HID * HID * 2);
  unsigned short* Wrt = (unsigned short*)alloc((size_t)L * HID * HID * 2);
  float* sc = (float*)alloc((size_t)L * HID * 4);
  float* sh = (float*)alloc((size_t)L * HID * 4);
  float* p = (float*)alloc((size_t)N * 2 * 4);
  float* q = (float*)alloc((size_t)N * 2 * 4);
  float* gcnt = (float*)alloc((size_t)NG * 4);
  uint2* binned = (uint2*)r;      // binned (8B*E) dead before r is first written
  float* out_node = r;            // r free by the time spmm2 runs

  hipMemsetAsync(bcnt, 0, (size_t)NB * 4, stream);
  k_bhist<<<256, 256, 0, stream>>>(dst, bcnt, E, NB);
  k_bscan<<<1, 256, 0, stream>>>(bcnt, bbase, bcur, NB);
  k_bscatter<<<256, 256, 0, stream>>>(src, dst, bcur, binned, E);
  k_bfill<<<NB, 256, 0, stream>>>(binned, bbase, row_ptr, inv_deg, col, N, NB);

  k_x2b<<<(N * HID / 4 + 255) / 256, 256, 0, stream>>>(x, xb, N * HID / 4);
  k_wconv<<<(L * HID * HID + 255) / 256, 256, 0, stream>>>(Wl, Wlt, L * HID * HID);
  k_wconv<<<(L * HID * HID + 255) / 256, 256, 0, stream>>>(Wr, Wrt, L * HID * HID);
  k_bnprep<<<(L * HID + 255) / 256, 256, 0, stream>>>(gamma, beta, rmean, rvar, sc, sh, L * HID);

  const unsigned short* hin = xb;
  for (int l = 0; l < L; ++l) {
    k_gemm<<<(N + 63) / 64, 256, 0, stream>>>(
        hin, Wlt + (size_t)l * HID * HID, Wrt + (size_t)l * HID * HID,
        b + (size_t)l * HID, ub, r, N);
    k_spmm_f<<<(N + 3) / 4, 256, 0, stream>>>(
        ub, r, row_ptr, col, inv_deg, sc + (size_t)l * HID, sh + (size_t)l * HID, hb, N);
    hin = hb;
  }
  k_pq<<<(N + 3) / 4, 256, 0, stream>>>(hin, Wl_out, Wr_out, p, q, N);
  k_spmm2<<<(N + 255) / 256, 256, 0, stream>>>(p, q, row_ptr, col, inv_deg, b_out, out_node, N);
  hipMemsetAsync(d_out, 0, (size_t)out_size * 4, stream);
  hipMemsetAsync(gcnt, 0, (size_t)NG * 4, stream);
  k_pool<<<(N + 255) / 256, 256, 0, stream>>>(out_node, batch, (float*)d_out, gcnt, N);
  k_div<<<(NG * 2 + 255) / 256, 256, 0, stream>>>((float*)d_out, gcnt, NG);
}

// Round 6
// 484.290 us; speedup vs baseline: 2.9185x; 1.2431x over previous
//
#include <hip/hip_runtime.h>

#define HID 128
#define BN_EPS 1e-5f

typedef short bf16x8 __attribute__((ext_vector_type(8)));
typedef float f32x4 __attribute__((ext_vector_type(4)));

__device__ inline unsigned short f2b(float f) {  // f32 -> bf16 RNE
  unsigned int u = __float_as_uint(f);
  unsigned int r = (u + 0x7fffu + ((u >> 16) & 1u)) >> 16;
  return (unsigned short)r;
}
__device__ inline float bl(unsigned int v) { return __uint_as_float(v << 16); }
__device__ inline float bh(unsigned int v) { return __uint_as_float(v & 0xffff0000u); }

// ---------------- bucketed CSR build (bucket = dst >> 8, 256 nodes/bucket) -------

__global__ void k_bhist(const int* __restrict__ dst, int* __restrict__ bcnt, int e, int nb) {
  __shared__ int h[256];
  for (int i = threadIdx.x; i < 256; i += blockDim.x) h[i] = 0;
  __syncthreads();
  int stride = gridDim.x * blockDim.x;
  for (int i = blockIdx.x * blockDim.x + threadIdx.x; i < e; i += stride)
    atomicAdd(&h[dst[i] >> 8], 1);
  __syncthreads();
  for (int i = threadIdx.x; i < nb; i += blockDim.x)
    if (h[i]) atomicAdd(&bcnt[i], h[i]);
}

// single block; nb <= 256
__global__ void k_bscan(const int* __restrict__ bcnt, int* __restrict__ base,
                        int* __restrict__ cur, int nb) {
  __shared__ int ws[4];
  int t = threadIdx.x;
  int v = (t < nb) ? bcnt[t] : 0;
  int lane = t & 63, wid = t >> 6;
  int x = v;
#pragma unroll
  for (int off = 1; off < 64; off <<= 1) {
    int y = __shfl_up(x, off, 64);
    if (lane >= off) x += y;
  }
  if (lane == 63) ws[wid] = x;
  __syncthreads();
  int add = 0;
  for (int w = 0; w < wid; ++w) add += ws[w];
  int incl = x + add;
  int excl = incl - v;
  if (t < nb) { base[t] = excl; cur[t] = excl; }
  if (t == nb - 1) base[nb] = incl;
}

__global__ void k_bscatter(const int* __restrict__ src, const int* __restrict__ dst,
                           int* __restrict__ cur, uint2* __restrict__ binned, int e) {
  __shared__ int bc[256];
  __shared__ int bo[256];
  int nchunk = (e + gridDim.x - 1) / gridDim.x;
  int c0 = blockIdx.x * nchunk;
  int c1 = min(c0 + nchunk, e);
  for (int i = threadIdx.x; i < 256; i += blockDim.x) bc[i] = 0;
  __syncthreads();
  for (int i = c0 + threadIdx.x; i < c1; i += blockDim.x)
    atomicAdd(&bc[dst[i] >> 8], 1);
  __syncthreads();
  for (int i = threadIdx.x; i < 256; i += blockDim.x) {
    int c = bc[i];
    bo[i] = c ? atomicAdd(&cur[i], c) : 0;
    bc[i] = 0;
  }
  __syncthreads();
  for (int i = c0 + threadIdx.x; i < c1; i += blockDim.x) {
    int d = dst[i];
    int b = d >> 8;
    int pos = bo[b] + atomicAdd(&bc[b], 1);
    binned[pos] = make_uint2((unsigned)src[i], (unsigned)d);
  }
}

// one block per bucket: row_ptr, inv_deg, col — all scatters LDS/L2-local
__global__ __launch_bounds__(256) void k_bfill(
    const uint2* __restrict__ binned, const int* __restrict__ base,
    int* __restrict__ row_ptr, float* __restrict__ inv_deg,
    int* __restrict__ col, int n, int nb) {
  __shared__ int cnt[256];
  __shared__ int cur[256];
  __shared__ int ws[4];
  int b = blockIdx.x;
  int t = threadIdx.x;
  int n0 = b << 8;
  int e0 = base[b], e1 = base[b + 1];
  cnt[t] = 0;
  __syncthreads();
  for (int i = e0 + t; i < e1; i += 256)
    atomicAdd(&cnt[binned[i].y & 255], 1);
  __syncthreads();
  int v = cnt[t];
  int lane = t & 63, wid = t >> 6;
  int x = v;
#pragma unroll
  for (int off = 1; off < 64; off <<= 1) {
    int y = __shfl_up(x, off, 64);
    if (lane >= off) x += y;
  }
  if (lane == 63) ws[wid] = x;
  __syncthreads();
  int add = 0;
  for (int w = 0; w < wid; ++w) add += ws[w];
  int excl = x - v + add;
  int node = n0 + t;
  if (node < n) {
    row_ptr[node] = e0 + excl;
    inv_deg[node] = 1.0f / (float)max(v, 1);
  }
  cur[t] = e0 + excl;
  __syncthreads();
  for (int i = e0 + t; i < e1; i += 256) {
    uint2 pr = binned[i];
    int pos = atomicAdd(&cur[pr.y & 255], 1);
    col[pos] = (int)pr.x;
  }
  if (b == 0 && t == 0) row_ptr[n] = base[nb];
}

// ---------------- small prep ----------------

__global__ void k_x2b(const float* __restrict__ x, unsigned short* __restrict__ xb, int n4) {
  int i = blockIdx.x * blockDim.x + threadIdx.x;
  if (i < n4) {
    float4 v = ((const float4*)x)[i];
    unsigned int lo = (unsigned int)f2b(v.x) | ((unsigned int)f2b(v.y) << 16);
    unsigned int hi = (unsigned int)f2b(v.z) | ((unsigned int)f2b(v.w) << 16);
    ((uint2*)xb)[i] = make_uint2(lo, hi);
  }
}

// W [nmats][128][128] (k-major) -> Wt [nmats][128][128] bf16 ([out_ch][k])
__global__ void k_wconv(const float* __restrict__ W, unsigned short* __restrict__ Wt, int total) {
  int i = blockIdx.x * blockDim.x + threadIdx.x;
  if (i < total) {
    int mat = i >> 14, rem = i & 16383, nn = rem >> 7, kk = rem & 127;
    Wt[i] = f2b(W[(mat << 14) + (kk << 7) + nn]);
  }
}

__global__ void k_bnprep(const float* __restrict__ g, const float* __restrict__ be,
                         const float* __restrict__ rm, const float* __restrict__ rv,
                         float* __restrict__ sc, float* __restrict__ sh, int n) {
  int i = blockIdx.x * blockDim.x + threadIdx.x;
  if (i < n) {
    float s = g[i] * rsqrtf(rv[i] + BN_EPS);
    sc[i] = s;
    sh[i] = be[i] - rm[i] * s;
  }
}

// -------- MFMA dense, weight-stationary: u = h@Wl (bf16), r = h@Wr + b (f32) -----
// wave w owns output channels [32w, 32w+32) of BOTH mats; all 16 A-frags live in
// VGPRs for the kernel's lifetime; block grid-strides over 16-node groups.

__global__ __launch_bounds__(256) void k_gemm2(
    const unsigned short* __restrict__ hb,   // [n][128] bf16
    const unsigned short* __restrict__ Wlt,  // [128][128] bf16 [out_ch][k]
    const unsigned short* __restrict__ Wrt,
    const float* __restrict__ bias,          // [128]
    unsigned short* __restrict__ u,          // [n][128] bf16
    float* __restrict__ r,                   // [n][128] f32
    int n, int ngroups) {
  int w = threadIdx.x >> 6;
  int lane = threadIdx.x & 63;
  int l15 = lane & 15, lhi = lane >> 4;

  bf16x8 aL[2][4], aR[2][4];
#pragma unroll
  for (int ms = 0; ms < 2; ++ms) {
    int row = (w << 5) + (ms << 4) + l15;
#pragma unroll
    for (int ks = 0; ks < 4; ++ks) {
      aL[ms][ks] = *(const bf16x8*)(Wlt + (row << 7) + (ks << 5) + (lhi << 3));
      aR[ms][ks] = *(const bf16x8*)(Wrt + (row << 7) + (ks << 5) + (lhi << 3));
    }
  }
  float4 bi[2];
#pragma unroll
  for (int ms = 0; ms < 2; ++ms)
    bi[ms] = *(const float4*)(bias + (w << 5) + (ms << 4) + (lhi << 2));

  for (int g = blockIdx.x; g < ngroups; g += gridDim.x) {
    int node = (g << 4) + l15;
    bool ok = node < n;
    int nsafe = ok ? node : 0;
    const unsigned short* hrow = hb + ((size_t)nsafe << 7) + (lhi << 3);
    bf16x8 bf0 = *(const bf16x8*)(hrow);
    bf16x8 bf1 = *(const bf16x8*)(hrow + 32);
    bf16x8 bf2 = *(const bf16x8*)(hrow + 64);
    bf16x8 bf3 = *(const bf16x8*)(hrow + 96);
    f32x4 accU[2], accR[2];
#pragma unroll
    for (int ms = 0; ms < 2; ++ms) { accU[ms] = (f32x4)(0.f); accR[ms] = (f32x4)(0.f); }
#pragma unroll
    for (int ms = 0; ms < 2; ++ms) {
      accU[ms] = __builtin_amdgcn_mfma_f32_16x16x32_bf16(aL[ms][0], bf0, accU[ms], 0, 0, 0);
      accU[ms] = __builtin_amdgcn_mfma_f32_16x16x32_bf16(aL[ms][1], bf1, accU[ms], 0, 0, 0);
      accU[ms] = __builtin_amdgcn_mfma_f32_16x16x32_bf16(aL[ms][2], bf2, accU[ms], 0, 0, 0);
      accU[ms] = __builtin_amdgcn_mfma_f32_16x16x32_bf16(aL[ms][3], bf3, accU[ms], 0, 0, 0);
      accR[ms] = __builtin_amdgcn_mfma_f32_16x16x32_bf16(aR[ms][0], bf0, accR[ms], 0, 0, 0);
      accR[ms] = __builtin_amdgcn_mfma_f32_16x16x32_bf16(aR[ms][1], bf1, accR[ms], 0, 0, 0);
      accR[ms] = __builtin_amdgcn_mfma_f32_16x16x32_bf16(aR[ms][2], bf2, accR[ms], 0, 0, 0);
      accR[ms] = __builtin_amdgcn_mfma_f32_16x16x32_bf16(aR[ms][3], bf3, accR[ms], 0, 0, 0);
    }
    if (ok) {
#pragma unroll
      for (int ms = 0; ms < 2; ++ms) {
        int ch = (w << 5) + (ms << 4) + (lhi << 2);
        unsigned int lo = (unsigned int)f2b(accU[ms][0]) | ((unsigned int)f2b(accU[ms][1]) << 16);
        unsigned int hi = (unsigned int)f2b(accU[ms][2]) | ((unsigned int)f2b(accU[ms][3]) << 16);
        *(uint2*)(u + ((size_t)node << 7) + ch) = make_uint2(lo, hi);
        *(float4*)(r + ((size_t)node << 7) + ch) =
            make_float4(accR[ms][0] + bi[ms].x, accR[ms][1] + bi[ms].y,
                        accR[ms][2] + bi[ms].z, accR[ms][3] + bi[ms].w);
      }
    }
  }
}

// ---------------- fused SpMM: hb_out = relu(bn(mean-gather(u) + r)) ----------------
// wave per node: 4 edge-slots x 16 channel-lanes (8 ch each); 32-edge unroll = 8
// gathers in flight per lane, 16-edge mid-tier, 4-edge tail.

__global__ __launch_bounds__(256) void k_spmm_f(
    const unsigned short* __restrict__ u, const float* __restrict__ r,
    const int* __restrict__ row_ptr, const int* __restrict__ col,
    const float* __restrict__ inv_deg, const float* __restrict__ sc,
    const float* __restrict__ sh, unsigned short* __restrict__ hbo, int n) {
  int node = blockIdx.x * 4 + (threadIdx.x >> 6);
  if (node >= n) return;
  int lane = threadIdx.x & 63;
  int slot = lane >> 4, c16 = lane & 15;
  int beg = row_ptr[node], end = row_ptr[node + 1];
  float a0 = 0, a1 = 0, a2 = 0, a3 = 0, a4 = 0, a5 = 0, a6 = 0, a7 = 0;
  const unsigned short* base = u + (c16 << 3);
  int e = beg;
  for (; e + 32 <= end; e += 32) {
    int s0 = col[e + slot];
    int s1 = col[e + 4 + slot];
    int s2 = col[e + 8 + slot];
    int s3 = col[e + 12 + slot];
    int s4 = col[e + 16 + slot];
    int s5 = col[e + 20 + slot];
    int s6 = col[e + 24 + slot];
    int s7 = col[e + 28 + slot];
    uint4 v0 = *(const uint4*)(base + ((size_t)s0 << 7));
    uint4 v1 = *(const uint4*)(base + ((size_t)s1 << 7));
    uint4 v2 = *(const uint4*)(base + ((size_t)s2 << 7));
    uint4 v3 = *(const uint4*)(base + ((size_t)s3 << 7));
    uint4 v4 = *(const uint4*)(base + ((size_t)s4 << 7));
    uint4 v5 = *(const uint4*)(base + ((size_t)s5 << 7));
    uint4 v6 = *(const uint4*)(base + ((size_t)s6 << 7));
    uint4 v7 = *(const uint4*)(base + ((size_t)s7 << 7));
    a0 += bl(v0.x); a1 += bh(v0.x); a2 += bl(v0.y); a3 += bh(v0.y);
    a4 += bl(v0.z); a5 += bh(v0.z); a6 += bl(v0.w); a7 += bh(v0.w);
    a0 += bl(v1.x); a1 += bh(v1.x); a2 += bl(v1.y); a3 += bh(v1.y);
    a4 += bl(v1.z); a5 += bh(v1.z); a6 += bl(v1.w); a7 += bh(v1.w);
    a0 += bl(v2.x); a1 += bh(v2.x); a2 += bl(v2.y); a3 += bh(v2.y);
    a4 += bl(v2.z); a5 += bh(v2.z); a6 += bl(v2.w); a7 += bh(v2.w);
    a0 += bl(v3.x); a1 += bh(v3.x); a2 += bl(v3.y); a3 += bh(v3.y);
    a4 += bl(v3.z); a5 += bh(v3.z); a6 += bl(v3.w); a7 += bh(v3.w);
    a0 += bl(v4.x); a1 += bh(v4.x); a2 += bl(v4.y); a3 += bh(v4.y);
    a4 += bl(v4.z); a5 += bh(v4.z); a6 += bl(v4.w); a7 += bh(v4.w);
    a0 += bl(v5.x); a1 += bh(v5.x); a2 += bl(v5.y); a3 += bh(v5.y);
    a4 += bl(v5.z); a5 += bh(v5.z); a6 += bl(v5.w); a7 += bh(v5.w);
    a0 += bl(v6.x); a1 += bh(v6.x); a2 += bl(v6.y); a3 += bh(v6.y);
    a4 += bl(v6.z); a5 += bh(v6.z); a6 += bl(v6.w); a7 += bh(v6.w);
    a0 += bl(v7.x); a1 += bh(v7.x); a2 += bl(v7.y); a3 += bh(v7.y);
    a4 += bl(v7.z); a5 += bh(v7.z); a6 += bl(v7.w); a7 += bh(v7.w);
  }
  for (; e + 16 <= end; e += 16) {
    int s0 = col[e + slot];
    int s1 = col[e + 4 + slot];
    int s2 = col[e + 8 + slot];
    int s3 = col[e + 12 + slot];
    uint4 v0 = *(const uint4*)(base + ((size_t)s0 << 7));
    uint4 v1 = *(const uint4*)(base + ((size_t)s1 << 7));
    uint4 v2 = *(const uint4*)(base + ((size_t)s2 << 7));
    uint4 v3 = *(const uint4*)(base + ((size_t)s3 << 7));
    a0 += bl(v0.x); a1 += bh(v0.x); a2 += bl(v0.y); a3 += bh(v0.y);
    a4 += bl(v0.z); a5 += bh(v0.z); a6 += bl(v0.w); a7 += bh(v0.w);
    a0 += bl(v1.x); a1 += bh(v1.x); a2 += bl(v1.y); a3 += bh(v1.y);
    a4 += bl(v1.z); a5 += bh(v1.z); a6 += bl(v1.w); a7 += bh(v1.w);
    a0 += bl(v2.x); a1 += bh(v2.x); a2 += bl(v2.y); a3 += bh(v2.y);
    a4 += bl(v2.z); a5 += bh(v2.z); a6 += bl(v2.w); a7 += bh(v2.w);
    a0 += bl(v3.x); a1 += bh(v3.x); a2 += bl(v3.y); a3 += bh(v3.y);
    a4 += bl(v3.z); a5 += bh(v3.z); a6 += bl(v3.w); a7 += bh(v3.w);
  }
  for (; e < end; e += 4) {
    int idx = e + slot;
    if (idx < end) {
      int s = col[idx];
      uint4 v = *(const uint4*)(base + ((size_t)s << 7));
      a0 += bl(v.x); a1 += bh(v.x); a2 += bl(v.y); a3 += bh(v.y);
      a4 += bl(v.z); a5 += bh(v.z); a6 += bl(v.w); a7 += bh(v.w);
    }
  }
#pragma unroll
  for (int st = 16; st <= 32; st <<= 1) {
    a0 += __shfl_xor(a0, st); a1 += __shfl_xor(a1, st);
    a2 += __shfl_xor(a2, st); a3 += __shfl_xor(a3, st);
    a4 += __shfl_xor(a4, st); a5 += __shfl_xor(a5, st);
    a6 += __shfl_xor(a6, st); a7 += __shfl_xor(a7, st);
  }
  if (slot == 0) {
    float w = inv_deg[node];
    int ch = c16 << 3;
    const float* rp = r + ((size_t)node << 7) + ch;
    float4 r0 = *(const float4*)rp;
    float4 r1 = *(const float4*)(rp + 4);
    float4 s0 = *(const float4*)(sc + ch);
    float4 s1 = *(const float4*)(sc + ch + 4);
    float4 h0 = *(const float4*)(sh + ch);
    float4 h1 = *(const float4*)(sh + ch + 4);
    float o0 = fmaxf((a0 * w + r0.x) * s0.x + h0.x, 0.f);
    float o1 = fmaxf((a1 * w + r0.y) * s0.y + h0.y, 0.f);
    float o2 = fmaxf((a2 * w + r0.z) * s0.z + h0.z, 0.f);
    float o3 = fmaxf((a3 * w + r0.w) * s0.w + h0.w, 0.f);
    float o4 = fmaxf((a4 * w + r1.x) * s1.x + h1.x, 0.f);
    float o5 = fmaxf((a5 * w + r1.y) * s1.y + h1.y, 0.f);
    float o6 = fmaxf((a6 * w + r1.z) * s1.z + h1.z, 0.f);
    float o7 = fmaxf((a7 * w + r1.w) * s1.w + h1.w, 0.f);
    unsigned int p0 = (unsigned int)f2b(o0) | ((unsigned int)f2b(o1) << 16);
    unsigned int p1 = (unsigned int)f2b(o2) | ((unsigned int)f2b(o3) << 16);
    unsigned int p2 = (unsigned int)f2b(o4) | ((unsigned int)f2b(o5) << 16);
    unsigned int p3 = (unsigned int)f2b(o6) | ((unsigned int)f2b(o7) << 16);
    *(uint4*)(hbo + ((size_t)node << 7) + ch) = make_uint4(p0, p1, p2, p3);
  }
}

// ---------------- final layer ----------------

__global__ void k_pq(const unsigned short* __restrict__ hb, const float* __restrict__ Wl_out,
                     const float* __restrict__ Wr_out, float* __restrict__ p,
                     float* __restrict__ q, int n) {
  int node = blockIdx.x * 4 + (threadIdx.x >> 6);
  if (node >= n) return;
  int lane = threadIdx.x & 63;
  unsigned int hv = *(const unsigned int*)(hb + ((size_t)node << 7) + (lane << 1));
  float hx = bl(hv), hy = bh(hv);
  float4 wl = *(const float4*)(Wl_out + (lane << 2)); // rows 2l,2l+1; cols 0,1
  float4 wr = *(const float4*)(Wr_out + (lane << 2));
  float p0 = hx * wl.x + hy * wl.z;
  float p1 = hx * wl.y + hy * wl.w;
  float q0 = hx * wr.x + hy * wr.z;
  float q1 = hx * wr.y + hy * wr.w;
#pragma unroll
  for (int off = 32; off > 0; off >>= 1) {
    p0 += __shfl_xor(p0, off, 64);
    p1 += __shfl_xor(p1, off, 64);
    q0 += __shfl_xor(q0, off, 64);
    q1 += __shfl_xor(q1, off, 64);
  }
  if (lane == 0) {
    *(float2*)(p + (size_t)node * 2) = make_float2(p0, p1);
    *(float2*)(q + (size_t)node * 2) = make_float2(q0, q1);
  }
}

__global__ void k_spmm2(const float* __restrict__ p, const float* __restrict__ q,
                        const int* __restrict__ row_ptr, const int* __restrict__ col,
                        const float* __restrict__ inv_deg, const float* __restrict__ b_out,
                        float* __restrict__ out_node, int n) {
  int i = blockIdx.x * blockDim.x + threadIdx.x;
  if (i >= n) return;
  int beg = row_ptr[i], end = row_ptr[i + 1];
  float a0 = 0.f, a1 = 0.f, b0 = 0.f, b1 = 0.f;
  int e = beg;
  for (; e + 2 <= end; e += 2) {
    float2 v0 = *(const float2*)(p + (size_t)col[e] * 2);
    float2 v1 = *(const float2*)(p + (size_t)col[e + 1] * 2);
    a0 += v0.x; a1 += v0.y; b0 += v1.x; b1 += v1.y;
  }
  if (e < end) {
    float2 v = *(const float2*)(p + (size_t)col[e] * 2);
    a0 += v.x; a1 += v.y;
  }
  float w = inv_deg[i];
  float2 qv = *(const float2*)(q + (size_t)i * 2);
  out_node[(size_t)i * 2] = (a0 + b0) * w + qv.x + b_out[0];
  out_node[(size_t)i * 2 + 1] = (a1 + b1) * w + qv.y + b_out[1];
}

// ---- pool: batch is SORTED -> wave-level segmented reduction, ~1 atomic per run ----

__global__ void k_pool(const float* __restrict__ out_node, const int* __restrict__ batch,
                       float* __restrict__ out, float* __restrict__ gcnt, int n) {
  int i = blockIdx.x * blockDim.x + threadIdx.x;
  int lane = threadIdx.x & 63;
  bool valid = i < n;
  int g = valid ? batch[i] : -1;
  float v0 = valid ? out_node[(size_t)i * 2] : 0.f;
  float v1 = valid ? out_node[(size_t)i * 2 + 1] : 0.f;
  float s0 = v0, s1 = v1;
#pragma unroll
  for (int off = 1; off < 64; off <<= 1) {
    float y0 = __shfl_up(s0, off, 64);
    float y1 = __shfl_up(s1, off, 64);
    if (lane >= off) { s0 += y0; s1 += y1; }
  }
  int gprev = __shfl_up(g, 1, 64);
  int gnext = __shfl_down(g, 1, 64);
  bool is_start = (lane == 0) || (g != gprev);
  bool is_end = valid && ((lane == 63) || (g != gnext));
  int startl = is_start ? lane : 0;
#pragma unroll
  for (int off = 1; off < 64; off <<= 1) {
    int y = __shfl_up(startl, off, 64);
    if (lane >= off) startl = max(startl, y);
  }
  int prevl = startl > 0 ? startl - 1 : 0;
  float t0 = __shfl(s0, prevl, 64);
  float t1 = __shfl(s1, prevl, 64);
  if (is_end) {
    float p0 = startl > 0 ? t0 : 0.f;
    float p1 = startl > 0 ? t1 : 0.f;
    atomicAdd(&out[g * 2], s0 - p0);
    atomicAdd(&out[g * 2 + 1], s1 - p1);
    atomicAdd(&gcnt[g], (float)(lane - startl + 1));
  }
}

__global__ void k_div(float* __restrict__ out, const float* __restrict__ gcnt, int ng) {
  int i = blockIdx.x * blockDim.x + threadIdx.x;
  if (i < ng * 2) out[i] /= fmaxf(gcnt[i >> 1], 1.0f);
}

// ---------------- launch ----------------

extern "C" void kernel_launch(void* const* d_in, const int* in_sizes, int n_in,
                              void* d_out, int out_size, void* d_ws, size_t ws_size,
                              hipStream_t stream) {
  const float* x = (const float*)d_in[0];
  const float* Wl = (const float*)d_in[1];
  const float* Wr = (const float*)d_in[2];
  const float* b = (const float*)d_in[3];
  const float* gamma = (const float*)d_in[4];
  const float* beta = (const float*)d_in[5];
  const float* rmean = (const float*)d_in[6];
  const float* rvar = (const float*)d_in[7];
  const float* Wl_out = (const float*)d_in[8];
  const float* Wr_out = (const float*)d_in[9];
  const float* b_out = (const float*)d_in[10];
  const int* eidx = (const int*)d_in[11];
  const int* batch = (const int*)d_in[12];

  const int N = in_sizes[0] / HID;
  const int E = in_sizes[11] / 2;
  const int L = in_sizes[1] / (HID * HID);
  const int NG = out_size / 2;
  const int NB = (N + 255) >> 8;  // nodes/bucket = 256; requires N <= 65536
  const int NGRP = (N + 15) >> 4;
  const int* src = eidx;
  const int* dst = eidx + E;

  char* ws = (char*)d_ws;
  size_t off = 0;
  auto alloc = [&](size_t bytes) {
    void* ptr = ws + off;
    off += (bytes + 255) & ~(size_t)255;
    return ptr;
  };
  int* row_ptr = (int*)alloc((size_t)(N + 1) * 4);
  int* bcnt = (int*)alloc((size_t)NB * 4);
  int* bbase = (int*)alloc((size_t)(NB + 1) * 4);
  int* bcur = (int*)alloc((size_t)NB * 4);
  int* col = (int*)alloc((size_t)E * 4);
  float* inv_deg = (float*)alloc((size_t)N * 4);
  unsigned short* xb = (unsigned short*)alloc((size_t)N * HID * 2);
  unsigned short* hb = (unsigned short*)alloc((size_t)N * HID * 2);
  unsigned short* ub = (unsigned short*)alloc((size_t)N * HID * 2);
  float* r = (float*)alloc((size_t)N * HID * 4);
  unsigned short* Wlt = (unsigned short*)alloc((size_t)L * HID * HID * 2);
  unsigned short* Wrt = (unsigned short*)alloc((size_t)L * HID * HID * 2);
  float* sc = (float*)alloc((size_t)L * HID * 4);
  float* sh = (float*)alloc((size_t)L * HID * 4);
  float* p = (float*)alloc((size_t)N * 2 * 4);
  float* q = (float*)alloc((size_t)N * 2 * 4);
  float* gcnt = (float*)alloc((size_t)NG * 4);
  uint2* binned = (uint2*)r;      // binned (8B*E) dead before r is first written
  float* out_node = r;            // r free by the time spmm2 runs

  hipMemsetAsync(bcnt, 0, (size_t)NB * 4, stream);
  k_bhist<<<256, 256, 0, stream>>>(dst, bcnt, E, NB);
  k_bscan<<<1, 256, 0, stream>>>(bcnt, bbase, bcur, NB);
  k_bscatter<<<256, 256, 0, stream>>>(src, dst, bcur, binned, E);
  k_bfill<<<NB, 256, 0, stream>>>(binned, bbase, row_ptr, inv_deg, col, N, NB);

  k_x2b<<<(N * HID / 4 + 255) / 256, 256, 0, stream>>>(x, xb, N * HID / 4);
  k_wconv<<<(L * HID * HID + 255) / 256, 256, 0, stream>>>(Wl, Wlt, L * HID * HID);
  k_wconv<<<(L * HID * HID + 255) / 256, 256, 0, stream>>>(Wr, Wrt, L * HID * HID);
  k_bnprep<<<(L * HID + 255) / 256, 256, 0, stream>>>(gamma, beta, rmean, rvar, sc, sh, L * HID);

  const unsigned short* hin = xb;
  for (int l = 0; l < L; ++l) {
    k_gemm2<<<512, 256, 0, stream>>>(
        hin, Wlt + (size_t)l * HID * HID, Wrt + (size_t)l * HID * HID,
        b + (size_t)l * HID, ub, r, N, NGRP);
    k_spmm_f<<<(N + 3) / 4, 256, 0, stream>>>(
        ub, r, row_ptr, col, inv_deg, sc + (size_t)l * HID, sh + (size_t)l * HID, hb, N);
    hin = hb;
  }
  k_pq<<<(N + 3) / 4, 256, 0, stream>>>(hin, Wl_out, Wr_out, p, q, N);
  k_spmm2<<<(N + 255) / 256, 256, 0, stream>>>(p, q, row_ptr, col, inv_deg, b_out, out_node, N);
  hipMemsetAsync(d_out, 0, (size_t)out_size * 4, stream);
  hipMemsetAsync(gcnt, 0, (size_t)NG * 4, stream);
  k_pool<<<(N + 255) / 256, 256, 0, stream>>>(out_node, batch, (float*)d_out, gcnt, N);
  k_div<<<(NG * 2 + 255) / 256, 256, 0, stream>>>((float*)d_out, gcnt, NG);
}

// Round 7
// 446.297 us; speedup vs baseline: 3.1669x; 1.0851x over previous
//
#include <hip/hip_runtime.h>

#define HID 128
#define BN_EPS 1e-5f

typedef short bf16x8 __attribute__((ext_vector_type(8)));
typedef float f32x4 __attribute__((ext_vector_type(4)));

__device__ inline unsigned short f2b(float f) {  // f32 -> bf16 RNE
  unsigned int u = __float_as_uint(f);
  unsigned int r = (u + 0x7fffu + ((u >> 16) & 1u)) >> 16;
  return (unsigned short)r;
}
__device__ inline float bl(unsigned int v) { return __uint_as_float(v << 16); }
__device__ inline float bh(unsigned int v) { return __uint_as_float(v & 0xffff0000u); }

// ---------------- bucketed CSR build (bucket = dst >> 8, 256 nodes/bucket) -------

__global__ void k_bhist(const int* __restrict__ dst, int* __restrict__ bcnt, int e, int nb) {
  __shared__ int h[256];
  for (int i = threadIdx.x; i < 256; i += blockDim.x) h[i] = 0;
  __syncthreads();
  int stride = gridDim.x * blockDim.x;
  for (int i = blockIdx.x * blockDim.x + threadIdx.x; i < e; i += stride)
    atomicAdd(&h[dst[i] >> 8], 1);
  __syncthreads();
  for (int i = threadIdx.x; i < nb; i += blockDim.x)
    if (h[i]) atomicAdd(&bcnt[i], h[i]);
}

// single block; nb <= 256
__global__ void k_bscan(const int* __restrict__ bcnt, int* __restrict__ base,
                        int* __restrict__ cur, int nb) {
  __shared__ int ws[4];
  int t = threadIdx.x;
  int v = (t < nb) ? bcnt[t] : 0;
  int lane = t & 63, wid = t >> 6;
  int x = v;
#pragma unroll
  for (int off = 1; off < 64; off <<= 1) {
    int y = __shfl_up(x, off, 64);
    if (lane >= off) x += y;
  }
  if (lane == 63) ws[wid] = x;
  __syncthreads();
  int add = 0;
  for (int w = 0; w < wid; ++w) add += ws[w];
  int incl = x + add;
  int excl = incl - v;
  if (t < nb) { base[t] = excl; cur[t] = excl; }
  if (t == nb - 1) base[nb] = incl;
}

__global__ void k_bscatter(const int* __restrict__ src, const int* __restrict__ dst,
                           int* __restrict__ cur, uint2* __restrict__ binned, int e) {
  __shared__ int bc[256];
  __shared__ int bo[256];
  int nchunk = (e + gridDim.x - 1) / gridDim.x;
  int c0 = blockIdx.x * nchunk;
  int c1 = min(c0 + nchunk, e);
  for (int i = threadIdx.x; i < 256; i += blockDim.x) bc[i] = 0;
  __syncthreads();
  for (int i = c0 + threadIdx.x; i < c1; i += blockDim.x)
    atomicAdd(&bc[dst[i] >> 8], 1);
  __syncthreads();
  for (int i = threadIdx.x; i < 256; i += blockDim.x) {
    int c = bc[i];
    bo[i] = c ? atomicAdd(&cur[i], c) : 0;
    bc[i] = 0;
  }
  __syncthreads();
  for (int i = c0 + threadIdx.x; i < c1; i += blockDim.x) {
    int d = dst[i];
    int b = d >> 8;
    int pos = bo[b] + atomicAdd(&bc[b], 1);
    binned[pos] = make_uint2((unsigned)src[i], (unsigned)d);
  }
}

// one block per bucket: row_ptr, inv_deg, col — all scatters LDS/L2-local
__global__ __launch_bounds__(256) void k_bfill(
    const uint2* __restrict__ binned, const int* __restrict__ base,
    int* __restrict__ row_ptr, float* __restrict__ inv_deg,
    int* __restrict__ col, int n, int nb) {
  __shared__ int cnt[256];
  __shared__ int cur[256];
  __shared__ int ws[4];
  int b = blockIdx.x;
  int t = threadIdx.x;
  int n0 = b << 8;
  int e0 = base[b], e1 = base[b + 1];
  cnt[t] = 0;
  __syncthreads();
  for (int i = e0 + t; i < e1; i += 256)
    atomicAdd(&cnt[binned[i].y & 255], 1);
  __syncthreads();
  int v = cnt[t];
  int lane = t & 63, wid = t >> 6;
  int x = v;
#pragma unroll
  for (int off = 1; off < 64; off <<= 1) {
    int y = __shfl_up(x, off, 64);
    if (lane >= off) x += y;
  }
  if (lane == 63) ws[wid] = x;
  __syncthreads();
  int add = 0;
  for (int w = 0; w < wid; ++w) add += ws[w];
  int excl = x - v + add;
  int node = n0 + t;
  if (node < n) {
    row_ptr[node] = e0 + excl;
    inv_deg[node] = 1.0f / (float)max(v, 1);
  }
  cur[t] = e0 + excl;
  __syncthreads();
  for (int i = e0 + t; i < e1; i += 256) {
    uint2 pr = binned[i];
    int pos = atomicAdd(&cur[pr.y & 255], 1);
    col[pos] = (int)pr.x;
  }
  if (b == 0 && t == 0) row_ptr[n] = base[nb];
}

// ------- merged prep: x->bf16, W->bf16 transposed, BN fold (one launch) ---------

__global__ void k_prep(const float* __restrict__ x, unsigned short* __restrict__ xb,
                       const float* __restrict__ Wl, const float* __restrict__ Wr,
                       unsigned short* __restrict__ Wlt, unsigned short* __restrict__ Wrt,
                       const float* __restrict__ g, const float* __restrict__ be,
                       const float* __restrict__ rm, const float* __restrict__ rv,
                       float* __restrict__ sc, float* __restrict__ sh,
                       int n4, int wtot, int bn) {
  int i = blockIdx.x * blockDim.x + threadIdx.x;
  if (i < n4) {
    float4 v = ((const float4*)x)[i];
    unsigned int lo = (unsigned int)f2b(v.x) | ((unsigned int)f2b(v.y) << 16);
    unsigned int hi = (unsigned int)f2b(v.z) | ((unsigned int)f2b(v.w) << 16);
    ((uint2*)xb)[i] = make_uint2(lo, hi);
  } else if (i < n4 + wtot) {
    int j = i - n4;
    int mat = j >> 14, rem = j & 16383, nn = rem >> 7, kk = rem & 127;
    int sidx = (mat << 14) + (kk << 7) + nn;
    Wlt[j] = f2b(Wl[sidx]);
    Wrt[j] = f2b(Wr[sidx]);
  } else if (i < n4 + wtot + bn) {
    int j = i - n4 - wtot;
    float s = g[j] * rsqrtf(rv[j] + BN_EPS);
    sc[j] = s;
    sh[j] = be[j] - rm[j] * s;
  }
}

// ------------- SpMM gather-only: aggb[i] = bf16(inv_deg[i]*sum hb[src]) ----------
// wave per node: 4 edge-slots x 16 channel-lanes (8ch/lane, 16B gathers), 16-edge unroll

__global__ __launch_bounds__(256) void k_spmm_g(
    const unsigned short* __restrict__ hbsrc, const int* __restrict__ row_ptr,
    const int* __restrict__ col, const float* __restrict__ inv_deg,
    unsigned short* __restrict__ aggb, int n) {
  int node = blockIdx.x * 4 + (threadIdx.x >> 6);
  if (node >= n) return;
  int lane = threadIdx.x & 63;
  int slot = lane >> 4, c16 = lane & 15;
  int beg = row_ptr[node], end = row_ptr[node + 1];
  float a0 = 0, a1 = 0, a2 = 0, a3 = 0, a4 = 0, a5 = 0, a6 = 0, a7 = 0;
  const unsigned short* base = hbsrc + (c16 << 3);
  int e = beg;
  for (; e + 16 <= end; e += 16) {
    int s0 = col[e + slot];
    int s1 = col[e + 4 + slot];
    int s2 = col[e + 8 + slot];
    int s3 = col[e + 12 + slot];
    uint4 v0 = *(const uint4*)(base + ((size_t)s0 << 7));
    uint4 v1 = *(const uint4*)(base + ((size_t)s1 << 7));
    uint4 v2 = *(const uint4*)(base + ((size_t)s2 << 7));
    uint4 v3 = *(const uint4*)(base + ((size_t)s3 << 7));
    a0 += bl(v0.x); a1 += bh(v0.x); a2 += bl(v0.y); a3 += bh(v0.y);
    a4 += bl(v0.z); a5 += bh(v0.z); a6 += bl(v0.w); a7 += bh(v0.w);
    a0 += bl(v1.x); a1 += bh(v1.x); a2 += bl(v1.y); a3 += bh(v1.y);
    a4 += bl(v1.z); a5 += bh(v1.z); a6 += bl(v1.w); a7 += bh(v1.w);
    a0 += bl(v2.x); a1 += bh(v2.x); a2 += bl(v2.y); a3 += bh(v2.y);
    a4 += bl(v2.z); a5 += bh(v2.z); a6 += bl(v2.w); a7 += bh(v2.w);
    a0 += bl(v3.x); a1 += bh(v3.x); a2 += bl(v3.y); a3 += bh(v3.y);
    a4 += bl(v3.z); a5 += bh(v3.z); a6 += bl(v3.w); a7 += bh(v3.w);
  }
  for (; e < end; e += 4) {
    int idx = e + slot;
    if (idx < end) {
      int s = col[idx];
      uint4 v = *(const uint4*)(base + ((size_t)s << 7));
      a0 += bl(v.x); a1 += bh(v.x); a2 += bl(v.y); a3 += bh(v.y);
      a4 += bl(v.z); a5 += bh(v.z); a6 += bl(v.w); a7 += bh(v.w);
    }
  }
#pragma unroll
  for (int st = 16; st <= 32; st <<= 1) {
    a0 += __shfl_xor(a0, st); a1 += __shfl_xor(a1, st);
    a2 += __shfl_xor(a2, st); a3 += __shfl_xor(a3, st);
    a4 += __shfl_xor(a4, st); a5 += __shfl_xor(a5, st);
    a6 += __shfl_xor(a6, st); a7 += __shfl_xor(a7, st);
  }
  if (slot == 0) {
    float w = inv_deg[node];
    unsigned int p0 = (unsigned int)f2b(a0 * w) | ((unsigned int)f2b(a1 * w) << 16);
    unsigned int p1 = (unsigned int)f2b(a2 * w) | ((unsigned int)f2b(a3 * w) << 16);
    unsigned int p2 = (unsigned int)f2b(a4 * w) | ((unsigned int)f2b(a5 * w) << 16);
    unsigned int p3 = (unsigned int)f2b(a6 * w) | ((unsigned int)f2b(a7 * w) << 16);
    *(uint4*)(aggb + ((size_t)node << 7) + (c16 << 3)) = make_uint4(p0, p1, p2, p3);
  }
}

// ---- MFMA layer GEMM, weight-stationary, fused BN+ReLU:
//      hbo = relu(bn(aggb@Wl + hb@Wr + b)) — both products share one accumulator.

__global__ __launch_bounds__(256) void k_gemm3(
    const unsigned short* __restrict__ aggb,  // [n][128] bf16
    const unsigned short* __restrict__ hbsrc, // [n][128] bf16
    const unsigned short* __restrict__ Wlt,   // [128][128] bf16 [out_ch][k]
    const unsigned short* __restrict__ Wrt,
    const float* __restrict__ bias, const float* __restrict__ sc,
    const float* __restrict__ sh, unsigned short* __restrict__ hbo,
    int n, int ngroups) {
  int w = threadIdx.x >> 6;
  int lane = threadIdx.x & 63;
  int l15 = lane & 15, lhi = lane >> 4;

  bf16x8 aL[2][4], aR[2][4];
#pragma unroll
  for (int ms = 0; ms < 2; ++ms) {
    int row = (w << 5) + (ms << 4) + l15;
#pragma unroll
    for (int ks = 0; ks < 4; ++ks) {
      aL[ms][ks] = *(const bf16x8*)(Wlt + (row << 7) + (ks << 5) + (lhi << 3));
      aR[ms][ks] = *(const bf16x8*)(Wrt + (row << 7) + (ks << 5) + (lhi << 3));
    }
  }
  float4 bi[2], scv[2], shv[2];
#pragma unroll
  for (int ms = 0; ms < 2; ++ms) {
    int ch = (w << 5) + (ms << 4) + (lhi << 2);
    bi[ms] = *(const float4*)(bias + ch);
    scv[ms] = *(const float4*)(sc + ch);
    shv[ms] = *(const float4*)(sh + ch);
  }

  for (int g = blockIdx.x; g < ngroups; g += gridDim.x) {
    int node = (g << 4) + l15;
    bool ok = node < n;
    int nsafe = ok ? node : 0;
    const unsigned short* arow = aggb + ((size_t)nsafe << 7) + (lhi << 3);
    const unsigned short* hrow = hbsrc + ((size_t)nsafe << 7) + (lhi << 3);
    bf16x8 bA0 = *(const bf16x8*)(arow);
    bf16x8 bA1 = *(const bf16x8*)(arow + 32);
    bf16x8 bA2 = *(const bf16x8*)(arow + 64);
    bf16x8 bA3 = *(const bf16x8*)(arow + 96);
    bf16x8 bH0 = *(const bf16x8*)(hrow);
    bf16x8 bH1 = *(const bf16x8*)(hrow + 32);
    bf16x8 bH2 = *(const bf16x8*)(hrow + 64);
    bf16x8 bH3 = *(const bf16x8*)(hrow + 96);
    f32x4 acc[2];
#pragma unroll
    for (int ms = 0; ms < 2; ++ms) acc[ms] = (f32x4)(0.f);
#pragma unroll
    for (int ms = 0; ms < 2; ++ms) {
      acc[ms] = __builtin_amdgcn_mfma_f32_16x16x32_bf16(aL[ms][0], bA0, acc[ms], 0, 0, 0);
      acc[ms] = __builtin_amdgcn_mfma_f32_16x16x32_bf16(aL[ms][1], bA1, acc[ms], 0, 0, 0);
      acc[ms] = __builtin_amdgcn_mfma_f32_16x16x32_bf16(aL[ms][2], bA2, acc[ms], 0, 0, 0);
      acc[ms] = __builtin_amdgcn_mfma_f32_16x16x32_bf16(aL[ms][3], bA3, acc[ms], 0, 0, 0);
      acc[ms] = __builtin_amdgcn_mfma_f32_16x16x32_bf16(aR[ms][0], bH0, acc[ms], 0, 0, 0);
      acc[ms] = __builtin_amdgcn_mfma_f32_16x16x32_bf16(aR[ms][1], bH1, acc[ms], 0, 0, 0);
      acc[ms] = __builtin_amdgcn_mfma_f32_16x16x32_bf16(aR[ms][2], bH2, acc[ms], 0, 0, 0);
      acc[ms] = __builtin_amdgcn_mfma_f32_16x16x32_bf16(aR[ms][3], bH3, acc[ms], 0, 0, 0);
    }
    if (ok) {
#pragma unroll
      for (int ms = 0; ms < 2; ++ms) {
        int ch = (w << 5) + (ms << 4) + (lhi << 2);
        float o0 = fmaxf((acc[ms][0] + bi[ms].x) * scv[ms].x + shv[ms].x, 0.f);
        float o1 = fmaxf((acc[ms][1] + bi[ms].y) * scv[ms].y + shv[ms].y, 0.f);
        float o2 = fmaxf((acc[ms][2] + bi[ms].z) * scv[ms].z + shv[ms].z, 0.f);
        float o3 = fmaxf((acc[ms][3] + bi[ms].w) * scv[ms].w + shv[ms].w, 0.f);
        unsigned int lo = (unsigned int)f2b(o0) | ((unsigned int)f2b(o1) << 16);
        unsigned int hi = (unsigned int)f2b(o2) | ((unsigned int)f2b(o3) << 16);
        *(uint2*)(hbo + ((size_t)node << 7) + ch) = make_uint2(lo, hi);
      }
    }
  }
}

// ---------------- final layer ----------------

__global__ void k_pq(const unsigned short* __restrict__ hb, const float* __restrict__ Wl_out,
                     const float* __restrict__ Wr_out, float* __restrict__ p,
                     float* __restrict__ q, int n) {
  int node = blockIdx.x * 4 + (threadIdx.x >> 6);
  if (node >= n) return;
  int lane = threadIdx.x & 63;
  unsigned int hv = *(const unsigned int*)(hb + ((size_t)node << 7) + (lane << 1));
  float hx = bl(hv), hy = bh(hv);
  float4 wl = *(const float4*)(Wl_out + (lane << 2)); // rows 2l,2l+1; cols 0,1
  float4 wr = *(const float4*)(Wr_out + (lane << 2));
  float p0 = hx * wl.x + hy * wl.z;
  float p1 = hx * wl.y + hy * wl.w;
  float q0 = hx * wr.x + hy * wr.z;
  float q1 = hx * wr.y + hy * wr.w;
#pragma unroll
  for (int off = 32; off > 0; off >>= 1) {
    p0 += __shfl_xor(p0, off, 64);
    p1 += __shfl_xor(p1, off, 64);
    q0 += __shfl_xor(q0, off, 64);
    q1 += __shfl_xor(q1, off, 64);
  }
  if (lane == 0) {
    *(float2*)(p + (size_t)node * 2) = make_float2(p0, p1);
    *(float2*)(q + (size_t)node * 2) = make_float2(q0, q1);
  }
}

// fused: per-node final conv output + segmented-scan mean-pool (batch is sorted)
__global__ void k_spmm2p(const float* __restrict__ p, const float* __restrict__ q,
                         const int* __restrict__ row_ptr, const int* __restrict__ col,
                         const float* __restrict__ inv_deg, const float* __restrict__ b_out,
                         const int* __restrict__ batch, float* __restrict__ out,
                         float* __restrict__ gcnt, int n) {
  int i = blockIdx.x * blockDim.x + threadIdx.x;
  int lane = threadIdx.x & 63;
  bool valid = i < n;
  float o0 = 0.f, o1 = 0.f;
  int g = -1;
  if (valid) {
    int beg = row_ptr[i], end = row_ptr[i + 1];
    float a0 = 0.f, a1 = 0.f, b0 = 0.f, b1 = 0.f;
    int e = beg;
    for (; e + 2 <= end; e += 2) {
      float2 v0 = *(const float2*)(p + (size_t)col[e] * 2);
      float2 v1 = *(const float2*)(p + (size_t)col[e + 1] * 2);
      a0 += v0.x; a1 += v0.y; b0 += v1.x; b1 += v1.y;
    }
    if (e < end) {
      float2 v = *(const float2*)(p + (size_t)col[e] * 2);
      a0 += v.x; a1 += v.y;
    }
    float w = inv_deg[i];
    float2 qv = *(const float2*)(q + (size_t)i * 2);
    o0 = (a0 + b0) * w + qv.x + b_out[0];
    o1 = (a1 + b1) * w + qv.y + b_out[1];
    g = batch[i];
  }
  float s0 = o0, s1 = o1;
#pragma unroll
  for (int off = 1; off < 64; off <<= 1) {
    float y0 = __shfl_up(s0, off, 64);
    float y1 = __shfl_up(s1, off, 64);
    if (lane >= off) { s0 += y0; s1 += y1; }
  }
  int gprev = __shfl_up(g, 1, 64);
  int gnext = __shfl_down(g, 1, 64);
  bool is_start = (lane == 0) || (g != gprev);
  bool is_end = valid && ((lane == 63) || (g != gnext));
  int startl = is_start ? lane : 0;
#pragma unroll
  for (int off = 1; off < 64; off <<= 1) {
    int y = __shfl_up(startl, off, 64);
    if (lane >= off) startl = max(startl, y);
  }
  int prevl = startl > 0 ? startl - 1 : 0;
  float t0 = __shfl(s0, prevl, 64);
  float t1 = __shfl(s1, prevl, 64);
  if (is_end) {
    float p0 = startl > 0 ? t0 : 0.f;
    float p1 = startl > 0 ? t1 : 0.f;
    atomicAdd(&out[g * 2], s0 - p0);
    atomicAdd(&out[g * 2 + 1], s1 - p1);
    atomicAdd(&gcnt[g], (float)(lane - startl + 1));
  }
}

__global__ void k_div(float* __restrict__ out, const float* __restrict__ gcnt, int ng) {
  int i = blockIdx.x * blockDim.x + threadIdx.x;
  if (i < ng * 2) out[i] /= fmaxf(gcnt[i >> 1], 1.0f);
}

// ---------------- launch ----------------

extern "C" void kernel_launch(void* const* d_in, const int* in_sizes, int n_in,
                              void* d_out, int out_size, void* d_ws, size_t ws_size,
                              hipStream_t stream) {
  const float* x = (const float*)d_in[0];
  const float* Wl = (const float*)d_in[1];
  const float* Wr = (const float*)d_in[2];
  const float* b = (const float*)d_in[3];
  const float* gamma = (const float*)d_in[4];
  const float* beta = (const float*)d_in[5];
  const float* rmean = (const float*)d_in[6];
  const float* rvar = (const float*)d_in[7];
  const float* Wl_out = (const float*)d_in[8];
  const float* Wr_out = (const float*)d_in[9];
  const float* b_out = (const float*)d_in[10];
  const int* eidx = (const int*)d_in[11];
  const int* batch = (const int*)d_in[12];

  const int N = in_sizes[0] / HID;
  const int E = in_sizes[11] / 2;
  const int L = in_sizes[1] / (HID * HID);
  const int NG = out_size / 2;
  const int NB = (N + 255) >> 8;  // nodes/bucket = 256; requires N <= 65536
  const int NGRP = (N + 15) >> 4;
  const int* src = eidx;
  const int* dst = eidx + E;

  char* ws = (char*)d_ws;
  size_t off = 0;
  auto alloc = [&](size_t bytes) {
    void* ptr = ws + off;
    off += (bytes + 255) & ~(size_t)255;
    return ptr;
  };
  int* row_ptr = (int*)alloc((size_t)(N + 1) * 4);
  int* bcnt = (int*)alloc((size_t)NB * 4);
  int* bbase = (int*)alloc((size_t)(NB + 1) * 4);
  int* bcur = (int*)alloc((size_t)NB * 4);
  int* col = (int*)alloc((size_t)E * 4);
  float* inv_deg = (float*)alloc((size_t)N * 4);
  unsigned short* xb = (unsigned short*)alloc((size_t)N * HID * 2);
  unsigned short* hb0 = (unsigned short*)alloc((size_t)N * HID * 2);
  unsigned short* hb1 = (unsigned short*)alloc((size_t)N * HID * 2);
  unsigned short* aggb = (unsigned short*)alloc((size_t)N * HID * 2);
  unsigned short* Wlt = (unsigned short*)alloc((size_t)L * HID * HID * 2);
  unsigned short* Wrt = (unsigned short*)alloc((size_t)L * HID * HID * 2);
  float* sc = (float*)alloc((size_t)L * HID * 4);
  float* sh = (float*)alloc((size_t)L * HID * 4);
  float* p = (float*)alloc((size_t)N * 2 * 4);
  float* q = (float*)alloc((size_t)N * 2 * 4);
  float* gcnt = (float*)alloc((size_t)NG * 4);
  uint2* binned = (uint2*)alloc((size_t)E * 8);  // dead after k_bfill

  hipMemsetAsync(bcnt, 0, (size_t)NB * 4, stream);
  k_bhist<<<256, 256, 0, stream>>>(dst, bcnt, E, NB);
  k_bscan<<<1, 256, 0, stream>>>(bcnt, bbase, bcur, NB);
  k_bscatter<<<256, 256, 0, stream>>>(src, dst, bcur, binned, E);
  k_bfill<<<NB, 256, 0, stream>>>(binned, bbase, row_ptr, inv_deg, col, N, NB);

  const int n4 = N * HID / 4;
  const int wtot = L * HID * HID;
  const int bn = L * HID;
  k_prep<<<(n4 + wtot + bn + 255) / 256, 256, 0, stream>>>(
      x, xb, Wl, Wr, Wlt, Wrt, gamma, beta, rmean, rvar, sc, sh, n4, wtot, bn);

  const unsigned short* hin = xb;
  for (int l = 0; l < L; ++l) {
    unsigned short* hnext = (l & 1) ? hb1 : hb0;
    k_spmm_g<<<(N + 3) / 4, 256, 0, stream>>>(hin, row_ptr, col, inv_deg, aggb, N);
    k_gemm3<<<512, 256, 0, stream>>>(
        aggb, hin, Wlt + (size_t)l * HID * HID, Wrt + (size_t)l * HID * HID,
        b + (size_t)l * HID, sc + (size_t)l * HID, sh + (size_t)l * HID,
        hnext, N, NGRP);
    hin = hnext;
  }
  k_pq<<<(N + 3) / 4, 256, 0, stream>>>(hin, Wl_out, Wr_out, p, q, N);
  hipMemsetAsync(d_out, 0, (size_t)out_size * 4, stream);
  hipMemsetAsync(gcnt, 0, (size_t)NG * 4, stream);
  k_spmm2p<<<(N + 255) / 256, 256, 0, stream>>>(
      p, q, row_ptr, col, inv_deg, b_out, batch, (float*)d_out, gcnt, N);
  k_div<<<(NG * 2 + 255) / 256, 256, 0, stream>>>((float*)d_out, gcnt, NG);
}